// Round 2
// baseline (568.411 us; speedup 1.0000x reference)
//
#include <hip/hip_runtime.h>
#include <cmath>

typedef __attribute__((ext_vector_type(8))) short bf16x8;
typedef __attribute__((ext_vector_type(4))) short s16x4;
typedef __attribute__((ext_vector_type(4))) float f32x4;

#define MFMA_BF16 __builtin_amdgcn_mfma_f32_16x16x32_bf16

__device__ __forceinline__ float bf2f(short s) {
    unsigned u = ((unsigned)(unsigned short)s) << 16;
    return __builtin_bit_cast(float, u);
}
__device__ __forceinline__ short f2bf(float f) {
    unsigned u = __builtin_bit_cast(unsigned, f);
    u += 0x7fffu + ((u >> 16) & 1u);   // RNE
    return (short)(u >> 16);
}

// fp32 -> bf16 conversion, 4 elements/thread
__global__ __launch_bounds__(256) void cvt_bf16(
    const float* __restrict__ src, short* __restrict__ dst, int n)
{
    int i = (blockIdx.x * 256 + threadIdx.x) * 4;
    if (i < n) {
        float4 v = *(const float4*)(src + i);
        s16x4 o;
        o[0] = f2bf(v.x); o[1] = f2bf(v.y); o[2] = f2bf(v.z); o[3] = f2bf(v.w);
        *(s16x4*)(dst + i) = o;
    }
}

// C = A @ W^T + bias. A: (M,K) bf16 row-major. W: (N,K) bf16 row-major. bias fp32.
// MODE=0: store bf16 row-major (M,N)
// MODE=1: store fp32 row-major (M,N)
// MODE=2: store bf16 transposed for V: out[((b*Hkv + n/128)*128 + n%128)*S + s]
template <int MODE>
__global__ __launch_bounds__(256) void gemm_bt(
    const short* __restrict__ A, const short* __restrict__ W,
    const float* __restrict__ bias, void* __restrict__ Cout,
    int M, int N, int K, int S, int Hkv)
{
    const int w    = threadIdx.x >> 6;
    const int lane = threadIdx.x & 63;
    const int l15  = lane & 15;
    const int quad = lane >> 4;
    const int m0 = blockIdx.y * 64 + (w >> 1) * 32;
    const int n0 = blockIdx.x * 64 + (w & 1) * 32;

    f32x4 c00 = {0.f, 0.f, 0.f, 0.f};
    f32x4 c01 = c00, c10 = c00, c11 = c00;

    const short* a0p = A + (size_t)(m0 + l15) * K + quad * 8;
    const short* a1p = a0p + (size_t)16 * K;
    const short* b0p = W + (size_t)(n0 + l15) * K + quad * 8;
    const short* b1p = b0p + (size_t)16 * K;

    for (int k = 0; k < K; k += 32) {
        bf16x8 a0 = *(const bf16x8*)(a0p + k);
        bf16x8 a1 = *(const bf16x8*)(a1p + k);
        bf16x8 b0 = *(const bf16x8*)(b0p + k);
        bf16x8 b1 = *(const bf16x8*)(b1p + k);
        c00 = MFMA_BF16(a0, b0, c00, 0, 0, 0);
        c01 = MFMA_BF16(a0, b1, c01, 0, 0, 0);
        c10 = MFMA_BF16(a1, b0, c10, 0, 0, 0);
        c11 = MFMA_BF16(a1, b1, c11, 0, 0, 0);
    }

#pragma unroll
    for (int i = 0; i < 2; i++) {
#pragma unroll
        for (int j = 0; j < 2; j++) {
            f32x4 c = (i == 0) ? ((j == 0) ? c00 : c01) : ((j == 0) ? c10 : c11);
            int col = n0 + j * 16 + l15;
            float bv = bias[col];
#pragma unroll
            for (int r = 0; r < 4; r++) {
                int row = m0 + i * 16 + quad * 4 + r;
                float v = c[r] + bv;
                if constexpr (MODE == 0) {
                    ((short*)Cout)[(size_t)row * N + col] = f2bf(v);
                } else if constexpr (MODE == 1) {
                    ((float*)Cout)[(size_t)row * N + col] = v;
                } else {
                    int b  = row / S, s = row - b * S;
                    int hk = col >> 7, dh = col & 127;   // Dh == 128
                    ((short*)Cout)[(size_t)((b * Hkv + hk) * 128 + dh) * S + s] = f2bf(v);
                }
            }
        }
    }
}

// Per-(token, head) LayerNorm over Dh=128 then RoPE. One wave per row-head.
// X: bf16 (B*S, H*128) row-major. Y: bf16 (B, H, S, 128). g/beta/cos/sin fp32.
__global__ __launch_bounds__(256) void ln_rope(
    const short* __restrict__ X, short* __restrict__ Y,
    const float* __restrict__ g, const float* __restrict__ bta,
    const float* __restrict__ cosp, const float* __restrict__ sinp,
    int H, int S)
{
    const int gw   = blockIdx.x * 4 + (threadIdx.x >> 6);
    const int lane = threadIdx.x & 63;
    const int h  = gw % H;
    const int rs = gw / H;          // b*S + s
    const int b  = rs / S;
    const int s  = rs - b * S;

    const short* x = X + ((size_t)rs * H + h) * 128;
    float x0 = bf2f(x[lane]), x1 = bf2f(x[lane + 64]);

    float sum = x0 + x1;
    float sq  = x0 * x0 + x1 * x1;
#pragma unroll
    for (int off = 32; off > 0; off >>= 1) {
        sum += __shfl_xor(sum, off, 64);
        sq  += __shfl_xor(sq, off, 64);
    }
    float mu  = sum * (1.f / 128.f);
    float var = sq * (1.f / 128.f) - mu * mu;
    float rinv = rsqrtf(var + 1e-5f);

    float y0 = (x0 - mu) * rinv * g[lane]      + bta[lane];
    float y1 = (x1 - mu) * rinv * g[lane + 64] + bta[lane + 64];

    float c0 = cosp[(size_t)s * 128 + lane];
    float c1 = cosp[(size_t)s * 128 + lane + 64];
    float s0 = sinp[(size_t)s * 128 + lane];
    float s1 = sinp[(size_t)s * 128 + lane + 64];

    // rotate_half: out[d] = y[d]*c[d] - y[d+64]*s[d]; out[d+64] = y[d+64]*c[d+64] + y[d]*s[d+64]
    float o0 = y0 * c0 - y1 * s0;
    float o1 = y1 * c1 + y0 * s1;

    short* yp = Y + ((size_t)(b * H + h) * S + s) * 128;
    yp[lane]      = f2bf(o0);
    yp[lane + 64] = f2bf(o1);
}

// Flash attention. Q: bf16 (B,H,S,128). Kt: bf16 (B,Hkv,S,128). Vt: bf16 (B,Hkv,128,S).
// O: bf16 (B, S, H*128). One wave = 16 q-rows; block = 4 waves = 64 q-rows.
__global__ __launch_bounds__(256) void attn(
    const short* __restrict__ Q, const short* __restrict__ Kt,
    const short* __restrict__ Vt, short* __restrict__ O,
    int S, int H, int Hkv, int nrep, float scale)
{
    __shared__ __align__(16) short P[4][16][32];

    const int w    = threadIdx.x >> 6;
    const int lane = threadIdx.x & 63;
    const int l15  = lane & 15;
    const int quad = lane >> 4;
    const int qblk = blockIdx.x;
    const int h    = blockIdx.y;
    const int b    = blockIdx.z;
    const int hk   = h / nrep;
    const int m0   = qblk * 64 + w * 16;

    const short* qb = Q  + (size_t)(b * H + h) * S * 128;
    const short* kb = Kt + (size_t)(b * Hkv + hk) * S * 128;
    const short* vb = Vt + (size_t)(b * Hkv + hk) * 128 * S;

    bf16x8 qf[4];
#pragma unroll
    for (int c = 0; c < 4; c++)
        qf[c] = *(const bf16x8*)(qb + (size_t)(m0 + l15) * 128 + c * 32 + quad * 8);

    f32x4 of[8];
#pragma unroll
    for (int c = 0; c < 8; c++) of[c] = f32x4{0.f, 0.f, 0.f, 0.f};
    float m_r[4], l_r[4];
#pragma unroll
    for (int r = 0; r < 4; r++) { m_r[r] = -1e30f; l_r[r] = 0.f; }

    const int nkt = qblk * 2 + 2;   // key tiles of 32, uniform across block
    for (int kt = 0; kt < nkt; kt++) {
        const int j0 = kt * 32;
        f32x4 s0 = {0.f, 0.f, 0.f, 0.f}, s1 = s0;
#pragma unroll
        for (int c = 0; c < 4; c++) {
            bf16x8 k0 = *(const bf16x8*)(kb + (size_t)(j0 + l15) * 128 + c * 32 + quad * 8);
            bf16x8 k1 = *(const bf16x8*)(kb + (size_t)(j0 + 16 + l15) * 128 + c * 32 + quad * 8);
            s0 = MFMA_BF16(qf[c], k0, s0, 0, 0, 0);
            s1 = MFMA_BF16(qf[c], k1, s1, 0, 0, 0);
        }

        float p0[4], p1[4], alpha[4];
#pragma unroll
        for (int r = 0; r < 4; r++) {
            int qpos = m0 + quad * 4 + r;
            float v0 = s0[r] * scale;
            float v1 = s1[r] * scale;
            if (j0 + l15 > qpos)      v0 = -1e30f;
            if (j0 + 16 + l15 > qpos) v1 = -1e30f;
            float mx = fmaxf(v0, v1);
            mx = fmaxf(mx, __shfl_xor(mx, 1, 64));
            mx = fmaxf(mx, __shfl_xor(mx, 2, 64));
            mx = fmaxf(mx, __shfl_xor(mx, 4, 64));
            mx = fmaxf(mx, __shfl_xor(mx, 8, 64));
            float mnew = fmaxf(m_r[r], mx);
            alpha[r] = __expf(m_r[r] - mnew);
            p0[r] = __expf(v0 - mnew);
            p1[r] = __expf(v1 - mnew);
            float rs_ = p0[r] + p1[r];
            rs_ += __shfl_xor(rs_, 1, 64);
            rs_ += __shfl_xor(rs_, 2, 64);
            rs_ += __shfl_xor(rs_, 4, 64);
            rs_ += __shfl_xor(rs_, 8, 64);
            l_r[r] = l_r[r] * alpha[r] + rs_;
            m_r[r] = mnew;
        }
#pragma unroll
        for (int c = 0; c < 8; c++) {
            f32x4 t = of[c];
            t[0] *= alpha[0]; t[1] *= alpha[1]; t[2] *= alpha[2]; t[3] *= alpha[3];
            of[c] = t;
        }
        // P (C-layout) -> LDS -> A-layout fragments
#pragma unroll
        for (int r = 0; r < 4; r++) {
            P[w][quad * 4 + r][l15]      = f2bf(p0[r]);
            P[w][quad * 4 + r][16 + l15] = f2bf(p1[r]);
        }
        __syncthreads();
        bf16x8 pa = *(const bf16x8*)(&P[w][l15][quad * 8]);
#pragma unroll
        for (int c = 0; c < 8; c++) {
            bf16x8 vf = *(const bf16x8*)(vb + (size_t)(c * 16 + l15) * S + j0 + quad * 8);
            of[c] = MFMA_BF16(pa, vf, of[c], 0, 0, 0);
        }
        __syncthreads();
    }

    const int HDh = H * 128;
#pragma unroll
    for (int c = 0; c < 8; c++) {
#pragma unroll
        for (int r = 0; r < 4; r++) {
            int row = m0 + quad * 4 + r;
            float v = of[c][r] / l_r[r];
            O[((size_t)b * S + row) * HDh + h * 128 + c * 16 + l15] = f2bf(v);
        }
    }
}

extern "C" void kernel_launch(void* const* d_in, const int* in_sizes, int n_in,
                              void* d_out, int out_size, void* d_ws, size_t ws_size,
                              hipStream_t stream) {
    const float* hs   = (const float*)d_in[0];
    const float* cosp = (const float*)d_in[1];
    const float* sinp = (const float*)d_in[2];
    const float* Wq   = (const float*)d_in[3];
    const float* bq   = (const float*)d_in[4];
    const float* Wk   = (const float*)d_in[5];
    const float* bk   = (const float*)d_in[6];
    const float* Wv   = (const float*)d_in[7];
    const float* bv   = (const float*)d_in[8];
    const float* Wo   = (const float*)d_in[9];
    const float* bo   = (const float*)d_in[10];
    const float* qg   = (const float*)d_in[11];
    const float* qb_  = (const float*)d_in[12];
    const float* kg   = (const float*)d_in[13];
    const float* kb_  = (const float*)d_in[14];

    const int Dh    = in_sizes[11];          // 128
    const int Dm    = in_sizes[10];          // 2048
    const int HDh   = in_sizes[4];           // 2048
    const int H     = HDh / Dh;              // 16
    const int HkvDh = in_sizes[6];           // 512
    const int Hkv   = HkvDh / Dh;            // 4
    const int S     = in_sizes[1] / Dh;      // 1024
    const int B     = in_sizes[0] / (S * Dm);// 2
    const int M     = B * S;                 // 2048
    const int nrep  = H / Hkv;               // 4

    // workspace layout (bf16 buffers; attn output aliases dead q-gemm buffer)
    char* ws = (char*)d_ws;
    short* hsb  = (short*)ws;  ws += (size_t)M * Dm      * 2;  // 8 MB
    short* Wqb  = (short*)ws;  ws += (size_t)HDh * Dm    * 2;  // 8 MB
    short* Wkb  = (short*)ws;  ws += (size_t)HkvDh * Dm  * 2;  // 2 MB
    short* Wvb  = (short*)ws;  ws += (size_t)HkvDh * Dm  * 2;  // 2 MB
    short* Wob  = (short*)ws;  ws += (size_t)Dm * HDh    * 2;  // 8 MB
    short* qg16 = (short*)ws;  ws += (size_t)M * HDh     * 2;  // 8 MB
    short* kg16 = (short*)ws;  ws += (size_t)M * HkvDh   * 2;  // 2 MB
    short* qbuf = (short*)ws;  ws += (size_t)M * HDh     * 2;  // 8 MB
    short* kbuf = (short*)ws;  ws += (size_t)M * HkvDh   * 2;  // 2 MB
    short* vbuf = (short*)ws;  ws += (size_t)M * HkvDh   * 2;  // 2 MB
    short* abuf = qg16;   // alias: q-gemm output dead after ln_rope

    dim3 blk(256);
    auto cvt = [&](const float* s, short* d, int n) {
        cvt_bf16<<<dim3((n / 4 + 255) / 256), blk, 0, stream>>>(s, d, n);
    };
    cvt(hs, hsb, M * Dm);
    cvt(Wq, Wqb, HDh * Dm);
    cvt(Wk, Wkb, HkvDh * Dm);
    cvt(Wv, Wvb, HkvDh * Dm);
    cvt(Wo, Wob, Dm * HDh);

    gemm_bt<0><<<dim3(HDh / 64,   M / 64), blk, 0, stream>>>(hsb, Wqb, bq, qg16, M, HDh,   Dm, S, Hkv);
    gemm_bt<0><<<dim3(HkvDh / 64, M / 64), blk, 0, stream>>>(hsb, Wkb, bk, kg16, M, HkvDh, Dm, S, Hkv);
    gemm_bt<2><<<dim3(HkvDh / 64, M / 64), blk, 0, stream>>>(hsb, Wvb, bv, vbuf, M, HkvDh, Dm, S, Hkv);

    ln_rope<<<dim3(M * H / 4),   blk, 0, stream>>>(qg16, qbuf, qg, qb_, cosp, sinp, H,   S);
    ln_rope<<<dim3(M * Hkv / 4), blk, 0, stream>>>(kg16, kbuf, kg, kb_, cosp, sinp, Hkv, S);

    const float scale = 1.0f / sqrtf((float)Dh);
    attn<<<dim3(S / 64, H, B), blk, 0, stream>>>(qbuf, kbuf, vbuf, abuf, S, H, Hkv, nrep, scale);

    gemm_bt<1><<<dim3(Dm / 64, M / 64), blk, 0, stream>>>(abuf, Wob, bo, (float*)d_out, M, Dm, HDh, S, Hkv);
}

// Round 3
// 559.680 us; speedup vs baseline: 1.0156x; 1.0156x over previous
//
#include <hip/hip_runtime.h>
#include <cmath>

typedef __attribute__((ext_vector_type(8))) short bf16x8;
typedef __attribute__((ext_vector_type(4))) short s16x4;
typedef __attribute__((ext_vector_type(4))) float f32x4;

#define MFMA_BF16 __builtin_amdgcn_mfma_f32_16x16x32_bf16

__device__ __forceinline__ float bf2f(short s) {
    unsigned u = ((unsigned)(unsigned short)s) << 16;
    return __builtin_bit_cast(float, u);
}
__device__ __forceinline__ short f2bf(float f) {
    unsigned u = __builtin_bit_cast(unsigned, f);
    u += 0x7fffu + ((u >> 16) & 1u);   // RNE
    return (short)(u >> 16);
}

// fp32 -> bf16 conversion, 4 elements/thread
__global__ __launch_bounds__(256) void cvt_bf16(
    const float* __restrict__ src, short* __restrict__ dst, int n)
{
    int i = (blockIdx.x * 256 + threadIdx.x) * 4;
    if (i < n) {
        float4 v = *(const float4*)(src + i);
        s16x4 o;
        o[0] = f2bf(v.x); o[1] = f2bf(v.y); o[2] = f2bf(v.z); o[3] = f2bf(v.w);
        *(s16x4*)(dst + i) = o;
    }
}

// Fused QKV projection: C = A @ Wp^T + bias, Wp = [Wq;Wk;Wv] packed (Nq+2*Nkv, K).
// n-segment decides destination: q -> bf16 (M,Nq); k -> bf16 (M,Nkv);
// v -> bf16 transposed (B,Hkv,128,S). Segment boundaries are 32-aligned so the
// branch is wave-tile-uniform.
__global__ __launch_bounds__(256) void gemm_qkv(
    const short* __restrict__ A, const short* __restrict__ Wp,
    const float* __restrict__ bq, const float* __restrict__ bk,
    const float* __restrict__ bv,
    short* __restrict__ qo, short* __restrict__ ko, short* __restrict__ vo,
    int M, int K, int S, int Hkv, int Nq, int Nkv)
{
    const int w    = threadIdx.x >> 6;
    const int lane = threadIdx.x & 63;
    const int l15  = lane & 15;
    const int quad = lane >> 4;
    const int m0 = blockIdx.y * 64 + (w >> 1) * 32;
    const int n0 = blockIdx.x * 64 + (w & 1) * 32;

    f32x4 c00 = {0.f, 0.f, 0.f, 0.f};
    f32x4 c01 = c00, c10 = c00, c11 = c00;

    const short* a0p = A + (size_t)(m0 + l15) * K + quad * 8;
    const short* a1p = a0p + (size_t)16 * K;
    const short* b0p = Wp + (size_t)(n0 + l15) * K + quad * 8;
    const short* b1p = b0p + (size_t)16 * K;

    for (int k = 0; k < K; k += 32) {
        bf16x8 a0 = *(const bf16x8*)(a0p + k);
        bf16x8 a1 = *(const bf16x8*)(a1p + k);
        bf16x8 b0 = *(const bf16x8*)(b0p + k);
        bf16x8 b1 = *(const bf16x8*)(b1p + k);
        c00 = MFMA_BF16(a0, b0, c00, 0, 0, 0);
        c01 = MFMA_BF16(a0, b1, c01, 0, 0, 0);
        c10 = MFMA_BF16(a1, b0, c10, 0, 0, 0);
        c11 = MFMA_BF16(a1, b1, c11, 0, 0, 0);
    }

#pragma unroll
    for (int i = 0; i < 2; i++) {
#pragma unroll
        for (int j = 0; j < 2; j++) {
            f32x4 c = (i == 0) ? ((j == 0) ? c00 : c01) : ((j == 0) ? c10 : c11);
            int col = n0 + j * 16 + l15;
#pragma unroll
            for (int r = 0; r < 4; r++) {
                int row = m0 + i * 16 + quad * 4 + r;
                if (col < Nq) {
                    ((short*)qo)[(size_t)row * Nq + col] = f2bf(c[r] + bq[col]);
                } else if (col < Nq + Nkv) {
                    int cn = col - Nq;
                    ((short*)ko)[(size_t)row * Nkv + cn] = f2bf(c[r] + bk[cn]);
                } else {
                    int cn = col - Nq - Nkv;
                    int b  = row / S, s = row - b * S;
                    int hk = cn >> 7, dh = cn & 127;   // Dh == 128
                    vo[(size_t)((b * Hkv + hk) * 128 + dh) * S + s] = f2bf(c[r] + bv[cn]);
                }
            }
        }
    }
}

// O-projection: C = A @ W^T + bias, fp32 out.
__global__ __launch_bounds__(256) void gemm_bt_f32(
    const short* __restrict__ A, const short* __restrict__ W,
    const float* __restrict__ bias, float* __restrict__ Cout,
    int M, int N, int K)
{
    const int w    = threadIdx.x >> 6;
    const int lane = threadIdx.x & 63;
    const int l15  = lane & 15;
    const int quad = lane >> 4;
    const int m0 = blockIdx.y * 64 + (w >> 1) * 32;
    const int n0 = blockIdx.x * 64 + (w & 1) * 32;

    f32x4 c00 = {0.f, 0.f, 0.f, 0.f};
    f32x4 c01 = c00, c10 = c00, c11 = c00;

    const short* a0p = A + (size_t)(m0 + l15) * K + quad * 8;
    const short* a1p = a0p + (size_t)16 * K;
    const short* b0p = W + (size_t)(n0 + l15) * K + quad * 8;
    const short* b1p = b0p + (size_t)16 * K;

    for (int k = 0; k < K; k += 32) {
        bf16x8 a0 = *(const bf16x8*)(a0p + k);
        bf16x8 a1 = *(const bf16x8*)(a1p + k);
        bf16x8 b0 = *(const bf16x8*)(b0p + k);
        bf16x8 b1 = *(const bf16x8*)(b1p + k);
        c00 = MFMA_BF16(a0, b0, c00, 0, 0, 0);
        c01 = MFMA_BF16(a0, b1, c01, 0, 0, 0);
        c10 = MFMA_BF16(a1, b0, c10, 0, 0, 0);
        c11 = MFMA_BF16(a1, b1, c11, 0, 0, 0);
    }

#pragma unroll
    for (int i = 0; i < 2; i++) {
#pragma unroll
        for (int j = 0; j < 2; j++) {
            f32x4 c = (i == 0) ? ((j == 0) ? c00 : c01) : ((j == 0) ? c10 : c11);
            int col = n0 + j * 16 + l15;
            float bvv = bias[col];
#pragma unroll
            for (int r = 0; r < 4; r++) {
                int row = m0 + i * 16 + quad * 4 + r;
                Cout[(size_t)row * N + col] = c[r] + bvv;
            }
        }
    }
}

// Per-(token, head) LayerNorm over Dh=128 then RoPE. One wave per row-head.
__global__ __launch_bounds__(256) void ln_rope(
    const short* __restrict__ X, short* __restrict__ Y,
    const float* __restrict__ g, const float* __restrict__ bta,
    const float* __restrict__ cosp, const float* __restrict__ sinp,
    int H, int S)
{
    const int gw   = blockIdx.x * 4 + (threadIdx.x >> 6);
    const int lane = threadIdx.x & 63;
    const int h  = gw % H;
    const int rs = gw / H;          // b*S + s
    const int b  = rs / S;
    const int s  = rs - b * S;

    const short* x = X + ((size_t)rs * H + h) * 128;
    float x0 = bf2f(x[lane]), x1 = bf2f(x[lane + 64]);

    float sum = x0 + x1;
    float sq  = x0 * x0 + x1 * x1;
#pragma unroll
    for (int off = 32; off > 0; off >>= 1) {
        sum += __shfl_xor(sum, off, 64);
        sq  += __shfl_xor(sq, off, 64);
    }
    float mu  = sum * (1.f / 128.f);
    float var = sq * (1.f / 128.f) - mu * mu;
    float rinv = rsqrtf(var + 1e-5f);

    float y0 = (x0 - mu) * rinv * g[lane]      + bta[lane];
    float y1 = (x1 - mu) * rinv * g[lane + 64] + bta[lane + 64];

    float c0 = cosp[(size_t)s * 128 + lane];
    float c1 = cosp[(size_t)s * 128 + lane + 64];
    float s0 = sinp[(size_t)s * 128 + lane];
    float s1 = sinp[(size_t)s * 128 + lane + 64];

    float o0 = y0 * c0 - y1 * s0;
    float o1 = y1 * c1 + y0 * s1;

    short* yp = Y + ((size_t)(b * H + h) * S + s) * 128;
    yp[lane]      = f2bf(o0);
    yp[lane + 64] = f2bf(o1);
}

// Flash attention, barrier-free. Q: bf16 (B,H,S,128). Kt: (B,Hkv,S,128).
// Vt: (B,Hkv,128,S). O: bf16 (B,S,H*128).
// One wave = 16 q-rows, 64-key tiles, wave-private LDS P scratch (no __syncthreads).
__global__ __launch_bounds__(256) void attn(
    const short* __restrict__ Q, const short* __restrict__ Kt,
    const short* __restrict__ Vt, short* __restrict__ O,
    int S, int H, int Hkv, int nrep, float scale)
{
    // stride 72 shorts: rows 16B-aligned (144B), per-quad write banks disjoint
    __shared__ __align__(16) short P[4][16][72];

    const int w    = threadIdx.x >> 6;
    const int lane = threadIdx.x & 63;
    const int l15  = lane & 15;
    const int quad = lane >> 4;
    const int qblk = blockIdx.x;
    const int h    = blockIdx.y;
    const int b    = blockIdx.z;
    const int hk   = h / nrep;
    const int m0   = qblk * 64 + w * 16;

    const short* qb = Q  + (size_t)(b * H + h) * S * 128;
    const short* kb = Kt + (size_t)(b * Hkv + hk) * S * 128;
    const short* vb = Vt + (size_t)(b * Hkv + hk) * 128 * S;

    bf16x8 qf[4];
#pragma unroll
    for (int c = 0; c < 4; c++)
        qf[c] = *(const bf16x8*)(qb + (size_t)(m0 + l15) * 128 + c * 32 + quad * 8);

    f32x4 of[8];
#pragma unroll
    for (int c = 0; c < 8; c++) of[c] = f32x4{0.f, 0.f, 0.f, 0.f};
    float m_r[4], l_r[4];
#pragma unroll
    for (int r = 0; r < 4; r++) { m_r[r] = -1e30f; l_r[r] = 0.f; }

    const int nkt = qblk + 1;   // 64-key tiles; wave w needs keys < m0+16 <= (qblk+1)*64
    for (int kt = 0; kt < nkt; kt++) {
        const int j0 = kt * 64;

        // S = Q K^T : 16 x 64 scores, 4 independent accumulator chains
        f32x4 sc[4];
#pragma unroll
        for (int t = 0; t < 4; t++) sc[t] = f32x4{0.f, 0.f, 0.f, 0.f};
#pragma unroll
        for (int c = 0; c < 4; c++) {
#pragma unroll
            for (int t = 0; t < 4; t++) {
                bf16x8 kf = *(const bf16x8*)(kb + (size_t)(j0 + t * 16 + l15) * 128 + c * 32 + quad * 8);
                sc[t] = MFMA_BF16(qf[c], kf, sc[t], 0, 0, 0);
            }
        }

        float p[4][4], alpha[4];
#pragma unroll
        for (int r = 0; r < 4; r++) {
            const int qpos = m0 + quad * 4 + r;
            float v[4];
#pragma unroll
            for (int t = 0; t < 4; t++) {
                v[t] = sc[t][r] * scale;
                if (j0 + t * 16 + l15 > qpos) v[t] = -1e30f;
            }
            float mx = fmaxf(fmaxf(v[0], v[1]), fmaxf(v[2], v[3]));
            mx = fmaxf(mx, __shfl_xor(mx, 1, 64));
            mx = fmaxf(mx, __shfl_xor(mx, 2, 64));
            mx = fmaxf(mx, __shfl_xor(mx, 4, 64));
            mx = fmaxf(mx, __shfl_xor(mx, 8, 64));
            float mnew = fmaxf(m_r[r], mx);
            alpha[r] = __expf(m_r[r] - mnew);
            float sum = 0.f;
#pragma unroll
            for (int t = 0; t < 4; t++) {
                p[t][r] = __expf(v[t] - mnew);
                sum += p[t][r];
            }
            sum += __shfl_xor(sum, 1, 64);
            sum += __shfl_xor(sum, 2, 64);
            sum += __shfl_xor(sum, 4, 64);
            sum += __shfl_xor(sum, 8, 64);
            l_r[r] = l_r[r] * alpha[r] + sum;
            m_r[r] = mnew;
        }

#pragma unroll
        for (int c = 0; c < 8; c++) {
            f32x4 t = of[c];
            t[0] *= alpha[0]; t[1] *= alpha[1]; t[2] *= alpha[2]; t[3] *= alpha[3];
            of[c] = t;
        }

        // P (C-layout) -> wave-private LDS -> A-layout fragments; no barrier needed
#pragma unroll
        for (int r = 0; r < 4; r++) {
#pragma unroll
            for (int t = 0; t < 4; t++)
                P[w][quad * 4 + r][t * 16 + l15] = f2bf(p[t][r]);
        }
        bf16x8 pa0 = *(const bf16x8*)(&P[w][l15][quad * 8]);
        bf16x8 pa1 = *(const bf16x8*)(&P[w][l15][32 + quad * 8]);

#pragma unroll
        for (int c = 0; c < 8; c++) {
            bf16x8 vf0 = *(const bf16x8*)(vb + (size_t)(c * 16 + l15) * S + j0 + quad * 8);
            bf16x8 vf1 = *(const bf16x8*)(vb + (size_t)(c * 16 + l15) * S + j0 + 32 + quad * 8);
            of[c] = MFMA_BF16(pa0, vf0, of[c], 0, 0, 0);
            of[c] = MFMA_BF16(pa1, vf1, of[c], 0, 0, 0);
        }
    }

    const int HDh = H * 128;
    float rinv[4];
#pragma unroll
    for (int r = 0; r < 4; r++) rinv[r] = 1.0f / l_r[r];
#pragma unroll
    for (int c = 0; c < 8; c++) {
#pragma unroll
        for (int r = 0; r < 4; r++) {
            int row = m0 + quad * 4 + r;
            O[((size_t)b * S + row) * HDh + h * 128 + c * 16 + l15] = f2bf(of[c][r] * rinv[r]);
        }
    }
}

extern "C" void kernel_launch(void* const* d_in, const int* in_sizes, int n_in,
                              void* d_out, int out_size, void* d_ws, size_t ws_size,
                              hipStream_t stream) {
    const float* hs   = (const float*)d_in[0];
    const float* cosp = (const float*)d_in[1];
    const float* sinp = (const float*)d_in[2];
    const float* Wq   = (const float*)d_in[3];
    const float* bq   = (const float*)d_in[4];
    const float* Wk   = (const float*)d_in[5];
    const float* bk   = (const float*)d_in[6];
    const float* Wv   = (const float*)d_in[7];
    const float* bv   = (const float*)d_in[8];
    const float* Wo   = (const float*)d_in[9];
    const float* bo   = (const float*)d_in[10];
    const float* qg   = (const float*)d_in[11];
    const float* qb_  = (const float*)d_in[12];
    const float* kg   = (const float*)d_in[13];
    const float* kb_  = (const float*)d_in[14];

    const int Dh    = in_sizes[11];          // 128
    const int Dm    = in_sizes[10];          // 2048
    const int HDh   = in_sizes[4];           // 2048
    const int H     = HDh / Dh;              // 16
    const int HkvDh = in_sizes[6];           // 512
    const int Hkv   = HkvDh / Dh;            // 4
    const int S     = in_sizes[1] / Dh;      // 1024
    const int B     = in_sizes[0] / (S * Dm);// 2
    const int M     = B * S;                 // 2048
    const int nrep  = H / Hkv;               // 4

    // workspace layout; Wqb/Wkb/Wvb contiguous => packed (HDh+2*HkvDh, Dm)
    char* ws = (char*)d_ws;
    short* hsb  = (short*)ws;  ws += (size_t)M * Dm      * 2;  // 8 MB
    short* Wqb  = (short*)ws;  ws += (size_t)HDh * Dm    * 2;  // 8 MB
    short* Wkb  = (short*)ws;  ws += (size_t)HkvDh * Dm  * 2;  // 2 MB
    short* Wvb  = (short*)ws;  ws += (size_t)HkvDh * Dm  * 2;  // 2 MB
    short* Wob  = (short*)ws;  ws += (size_t)Dm * HDh    * 2;  // 8 MB
    short* qg16 = (short*)ws;  ws += (size_t)M * HDh     * 2;  // 8 MB
    short* kg16 = (short*)ws;  ws += (size_t)M * HkvDh   * 2;  // 2 MB
    short* qbuf = (short*)ws;  ws += (size_t)M * HDh     * 2;  // 8 MB
    short* kbuf = (short*)ws;  ws += (size_t)M * HkvDh   * 2;  // 2 MB
    short* vbuf = (short*)ws;  ws += (size_t)M * HkvDh   * 2;  // 2 MB
    short* abuf = qg16;   // alias: q-gemm output dead after ln_rope

    dim3 blk(256);
    auto cvt = [&](const float* s, short* d, int n) {
        cvt_bf16<<<dim3((n / 4 + 255) / 256), blk, 0, stream>>>(s, d, n);
    };
    cvt(hs, hsb, M * Dm);
    cvt(Wq, Wqb, HDh * Dm);
    cvt(Wk, Wkb, HkvDh * Dm);
    cvt(Wv, Wvb, HkvDh * Dm);
    cvt(Wo, Wob, Dm * HDh);

    const int Ntot = HDh + 2 * HkvDh;  // 3072
    gemm_qkv<<<dim3(Ntot / 64, M / 64), blk, 0, stream>>>(
        hsb, Wqb, bq, bk, bv, qg16, kg16, vbuf, M, Dm, S, Hkv, HDh, HkvDh);

    ln_rope<<<dim3(M * H / 4),   blk, 0, stream>>>(qg16, qbuf, qg, qb_, cosp, sinp, H,   S);
    ln_rope<<<dim3(M * Hkv / 4), blk, 0, stream>>>(kg16, kbuf, kg, kb_, cosp, sinp, Hkv, S);

    const float scale = 1.0f / sqrtf((float)Dh);
    attn<<<dim3(S / 64, H, B), blk, 0, stream>>>(qbuf, kbuf, vbuf, abuf, S, H, Hkv, nrep, scale);

    gemm_bt_f32<<<dim3(Dm / 64, M / 64), blk, 0, stream>>>(abuf, Wob, bo, (float*)d_out, M, Dm, HDh);
}

// Round 4
// 376.170 us; speedup vs baseline: 1.5110x; 1.4878x over previous
//
#include <hip/hip_runtime.h>
#include <cmath>

typedef __attribute__((ext_vector_type(8))) short bf16x8;
typedef __attribute__((ext_vector_type(4))) short s16x4;
typedef __attribute__((ext_vector_type(4))) float f32x4;

#define MFMA_BF16 __builtin_amdgcn_mfma_f32_16x16x32_bf16

__device__ __forceinline__ float bf2f(short s) {
    unsigned u = ((unsigned)(unsigned short)s) << 16;
    return __builtin_bit_cast(float, u);
}
__device__ __forceinline__ short f2bf(float f) {
    unsigned u = __builtin_bit_cast(unsigned, f);
    u += 0x7fffu + ((u >> 16) & 1u);   // RNE
    return (short)(u >> 16);
}

// fp32 -> bf16 conversion, 4 elements/thread
__global__ __launch_bounds__(256) void cvt_bf16(
    const float* __restrict__ src, short* __restrict__ dst, int n)
{
    int i = (blockIdx.x * 256 + threadIdx.x) * 4;
    if (i < n) {
        float4 v = *(const float4*)(src + i);
        s16x4 o;
        o[0] = f2bf(v.x); o[1] = f2bf(v.y); o[2] = f2bf(v.z); o[3] = f2bf(v.w);
        *(s16x4*)(dst + i) = o;
    }
}

// Stage a 128x32 bf16 tile (8 KB) from global row-major (stride gstride) into
// LDS [128][32] row-major via global_load_lds width=16. Each wave stages 2
// contiguous 1-KB chunks (16 rows each); LDS dest is wave-uniform base +
// lane*16B, matching the lane order of the global addresses (m104 caveat).
__device__ __forceinline__ void stage128x32(
    const short* __restrict__ g, int gstride, short* l,
    int w, int lane, int kofs)
{
    const int row0 = 32 * w + (lane >> 2);
    const int kq   = (lane & 3) * 8;
#pragma unroll
    for (int i = 0; i < 2; i++) {
        const short* gp = g + (size_t)(row0 + 16 * i) * gstride + kofs + kq;
        short* lp = l + (32 * w + 16 * i) * 32 + lane * 8;
        __builtin_amdgcn_global_load_lds(
            (const __attribute__((address_space(1))) unsigned int*)gp,
            (__attribute__((address_space(3))) unsigned int*)lp, 16, 0, 0);
    }
}

// m97-style 128x128-tile GEMM body: C = A @ W^T (+bias in epilogue).
// 4 waves in 2x2, each wave 64x64 (4x4 MFMA accs), BK=32, double-buffered LDS,
// one barrier per K-iter (prefetch of tile kt+1 issued before compute of kt,
// drained at the post-compute barrier).
// MODE 0: QKV fused epilogue (q/k bf16 row-major, v bf16 transposed (B,Hkv,128,S))
// MODE 1: fp32 out + bias
template <int MODE>
__global__ __launch_bounds__(256) void gemm128(
    const short* __restrict__ A, const short* __restrict__ W,
    const float* __restrict__ bq, const float* __restrict__ bk,
    const float* __restrict__ bv,
    short* __restrict__ qo, short* __restrict__ ko, short* __restrict__ vo,
    float* __restrict__ fo,
    int M, int K, int S, int Hkv, int Nq, int Nkv, int N)
{
    __shared__ __align__(16) short As[2][128 * 32];
    __shared__ __align__(16) short Bs[2][128 * 32];

    const int w    = threadIdx.x >> 6;
    const int lane = threadIdx.x & 63;
    const int l15  = lane & 15;
    const int quad = lane >> 4;
    const int wy   = w >> 1;
    const int wx   = w & 1;
    const int m0   = blockIdx.y * 128;
    const int n0   = blockIdx.x * 128;

    f32x4 acc[4][4];
#pragma unroll
    for (int i = 0; i < 4; i++)
#pragma unroll
        for (int j = 0; j < 4; j++) acc[i][j] = f32x4{0.f, 0.f, 0.f, 0.f};

    const short* Ab = A + (size_t)m0 * K;
    const short* Wb = W + (size_t)n0 * K;

    const int nk = K / 32;
    stage128x32(Ab, K, As[0], w, lane, 0);
    stage128x32(Wb, K, Bs[0], w, lane, 0);
    __syncthreads();

    for (int kt = 0; kt < nk; kt++) {
        const int cur = kt & 1;
        if (kt + 1 < nk) {
            stage128x32(Ab, K, As[cur ^ 1], w, lane, (kt + 1) * 32);
            stage128x32(Wb, K, Bs[cur ^ 1], w, lane, (kt + 1) * 32);
        }
        bf16x8 af[4], bfr[4];
#pragma unroll
        for (int i = 0; i < 4; i++)
            af[i] = *(const bf16x8*)(As[cur] + (wy * 64 + i * 16 + l15) * 32 + quad * 8);
#pragma unroll
        for (int j = 0; j < 4; j++)
            bfr[j] = *(const bf16x8*)(Bs[cur] + (wx * 64 + j * 16 + l15) * 32 + quad * 8);
#pragma unroll
        for (int i = 0; i < 4; i++)
#pragma unroll
            for (int j = 0; j < 4; j++)
                acc[i][j] = MFMA_BF16(af[i], bfr[j], acc[i][j], 0, 0, 0);
        __syncthreads();
    }

#pragma unroll
    for (int i = 0; i < 4; i++) {
#pragma unroll
        for (int j = 0; j < 4; j++) {
            const int col = n0 + wx * 64 + j * 16 + l15;
#pragma unroll
            for (int r = 0; r < 4; r++) {
                const int row = m0 + wy * 64 + i * 16 + quad * 4 + r;
                float v = acc[i][j][r];
                if constexpr (MODE == 0) {
                    if (col < Nq) {
                        qo[(size_t)row * Nq + col] = f2bf(v + bq[col]);
                    } else if (col < Nq + Nkv) {
                        int cn = col - Nq;
                        ko[(size_t)row * Nkv + cn] = f2bf(v + bk[cn]);
                    } else {
                        int cn = col - Nq - Nkv;
                        int b  = row / S, s = row - b * S;
                        int hk = cn >> 7, dh = cn & 127;   // Dh == 128
                        vo[(size_t)((b * Hkv + hk) * 128 + dh) * S + s] = f2bf(v + bv[cn]);
                    }
                } else {
                    fo[(size_t)row * N + col] = v + bq[col];
                }
            }
        }
    }
}

// Per-(token, head) LayerNorm over Dh=128 then RoPE. One wave per row-head.
__global__ __launch_bounds__(256) void ln_rope(
    const short* __restrict__ X, short* __restrict__ Y,
    const float* __restrict__ g, const float* __restrict__ bta,
    const float* __restrict__ cosp, const float* __restrict__ sinp,
    int H, int S)
{
    const int gw   = blockIdx.x * 4 + (threadIdx.x >> 6);
    const int lane = threadIdx.x & 63;
    const int h  = gw % H;
    const int rs = gw / H;          // b*S + s
    const int b  = rs / S;
    const int s  = rs - b * S;

    const short* x = X + ((size_t)rs * H + h) * 128;
    float x0 = bf2f(x[lane]), x1 = bf2f(x[lane + 64]);

    float sum = x0 + x1;
    float sq  = x0 * x0 + x1 * x1;
#pragma unroll
    for (int off = 32; off > 0; off >>= 1) {
        sum += __shfl_xor(sum, off, 64);
        sq  += __shfl_xor(sq, off, 64);
    }
    float mu  = sum * (1.f / 128.f);
    float var = sq * (1.f / 128.f) - mu * mu;
    float rinv = rsqrtf(var + 1e-5f);

    float y0 = (x0 - mu) * rinv * g[lane]      + bta[lane];
    float y1 = (x1 - mu) * rinv * g[lane + 64] + bta[lane + 64];

    float c0 = cosp[(size_t)s * 128 + lane];
    float c1 = cosp[(size_t)s * 128 + lane + 64];
    float s0 = sinp[(size_t)s * 128 + lane];
    float s1 = sinp[(size_t)s * 128 + lane + 64];

    float o0 = y0 * c0 - y1 * s0;
    float o1 = y1 * c1 + y0 * s1;

    short* yp = Y + ((size_t)(b * H + h) * S + s) * 128;
    yp[lane]      = f2bf(o0);
    yp[lane + 64] = f2bf(o1);
}

// Flash attention, barrier-free. Q: bf16 (B,H,S,128). Kt: (B,Hkv,S,128).
// Vt: (B,Hkv,128,S). O: bf16 (B,S,H*128).
// One wave = 16 q-rows, 64-key tiles, wave-private LDS P scratch (no __syncthreads).
__global__ __launch_bounds__(256) void attn(
    const short* __restrict__ Q, const short* __restrict__ Kt,
    const short* __restrict__ Vt, short* __restrict__ O,
    int S, int H, int Hkv, int nrep, float scale)
{
    __shared__ __align__(16) short P[4][16][72];

    const int w    = threadIdx.x >> 6;
    const int lane = threadIdx.x & 63;
    const int l15  = lane & 15;
    const int quad = lane >> 4;
    const int qblk = blockIdx.x;
    const int h    = blockIdx.y;
    const int b    = blockIdx.z;
    const int hk   = h / nrep;
    const int m0   = qblk * 64 + w * 16;

    const short* qb = Q  + (size_t)(b * H + h) * S * 128;
    const short* kb = Kt + (size_t)(b * Hkv + hk) * S * 128;
    const short* vb = Vt + (size_t)(b * Hkv + hk) * 128 * S;

    bf16x8 qf[4];
#pragma unroll
    for (int c = 0; c < 4; c++)
        qf[c] = *(const bf16x8*)(qb + (size_t)(m0 + l15) * 128 + c * 32 + quad * 8);

    f32x4 of[8];
#pragma unroll
    for (int c = 0; c < 8; c++) of[c] = f32x4{0.f, 0.f, 0.f, 0.f};
    float m_r[4], l_r[4];
#pragma unroll
    for (int r = 0; r < 4; r++) { m_r[r] = -1e30f; l_r[r] = 0.f; }

    const int nkt = qblk + 1;
    for (int kt = 0; kt < nkt; kt++) {
        const int j0 = kt * 64;

        f32x4 sc[4];
#pragma unroll
        for (int t = 0; t < 4; t++) sc[t] = f32x4{0.f, 0.f, 0.f, 0.f};
#pragma unroll
        for (int c = 0; c < 4; c++) {
#pragma unroll
            for (int t = 0; t < 4; t++) {
                bf16x8 kf = *(const bf16x8*)(kb + (size_t)(j0 + t * 16 + l15) * 128 + c * 32 + quad * 8);
                sc[t] = MFMA_BF16(qf[c], kf, sc[t], 0, 0, 0);
            }
        }

        float p[4][4], alpha[4];
#pragma unroll
        for (int r = 0; r < 4; r++) {
            const int qpos = m0 + quad * 4 + r;
            float v[4];
#pragma unroll
            for (int t = 0; t < 4; t++) {
                v[t] = sc[t][r] * scale;
                if (j0 + t * 16 + l15 > qpos) v[t] = -1e30f;
            }
            float mx = fmaxf(fmaxf(v[0], v[1]), fmaxf(v[2], v[3]));
            mx = fmaxf(mx, __shfl_xor(mx, 1, 64));
            mx = fmaxf(mx, __shfl_xor(mx, 2, 64));
            mx = fmaxf(mx, __shfl_xor(mx, 4, 64));
            mx = fmaxf(mx, __shfl_xor(mx, 8, 64));
            float mnew = fmaxf(m_r[r], mx);
            alpha[r] = __expf(m_r[r] - mnew);
            float sum = 0.f;
#pragma unroll
            for (int t = 0; t < 4; t++) {
                p[t][r] = __expf(v[t] - mnew);
                sum += p[t][r];
            }
            sum += __shfl_xor(sum, 1, 64);
            sum += __shfl_xor(sum, 2, 64);
            sum += __shfl_xor(sum, 4, 64);
            sum += __shfl_xor(sum, 8, 64);
            l_r[r] = l_r[r] * alpha[r] + sum;
            m_r[r] = mnew;
        }

#pragma unroll
        for (int c = 0; c < 8; c++) {
            f32x4 t = of[c];
            t[0] *= alpha[0]; t[1] *= alpha[1]; t[2] *= alpha[2]; t[3] *= alpha[3];
            of[c] = t;
        }

#pragma unroll
        for (int r = 0; r < 4; r++) {
#pragma unroll
            for (int t = 0; t < 4; t++)
                P[w][quad * 4 + r][t * 16 + l15] = f2bf(p[t][r]);
        }
        bf16x8 pa0 = *(const bf16x8*)(&P[w][l15][quad * 8]);
        bf16x8 pa1 = *(const bf16x8*)(&P[w][l15][32 + quad * 8]);

#pragma unroll
        for (int c = 0; c < 8; c++) {
            bf16x8 vf0 = *(const bf16x8*)(vb + (size_t)(c * 16 + l15) * S + j0 + quad * 8);
            bf16x8 vf1 = *(const bf16x8*)(vb + (size_t)(c * 16 + l15) * S + j0 + 32 + quad * 8);
            of[c] = MFMA_BF16(pa0, vf0, of[c], 0, 0, 0);
            of[c] = MFMA_BF16(pa1, vf1, of[c], 0, 0, 0);
        }
    }

    const int HDh = H * 128;
    float rinv[4];
#pragma unroll
    for (int r = 0; r < 4; r++) rinv[r] = 1.0f / l_r[r];
#pragma unroll
    for (int c = 0; c < 8; c++) {
#pragma unroll
        for (int r = 0; r < 4; r++) {
            int row = m0 + quad * 4 + r;
            O[((size_t)b * S + row) * HDh + h * 128 + c * 16 + l15] = f2bf(of[c][r] * rinv[r]);
        }
    }
}

extern "C" void kernel_launch(void* const* d_in, const int* in_sizes, int n_in,
                              void* d_out, int out_size, void* d_ws, size_t ws_size,
                              hipStream_t stream) {
    const float* hs   = (const float*)d_in[0];
    const float* cosp = (const float*)d_in[1];
    const float* sinp = (const float*)d_in[2];
    const float* Wq   = (const float*)d_in[3];
    const float* bq   = (const float*)d_in[4];
    const float* Wk   = (const float*)d_in[5];
    const float* bk   = (const float*)d_in[6];
    const float* Wv   = (const float*)d_in[7];
    const float* bv   = (const float*)d_in[8];
    const float* Wo   = (const float*)d_in[9];
    const float* bo   = (const float*)d_in[10];
    const float* qg   = (const float*)d_in[11];
    const float* qb_  = (const float*)d_in[12];
    const float* kg   = (const float*)d_in[13];
    const float* kb_  = (const float*)d_in[14];

    const int Dh    = in_sizes[11];          // 128
    const int Dm    = in_sizes[10];          // 2048
    const int HDh   = in_sizes[4];           // 2048
    const int H     = HDh / Dh;              // 16
    const int HkvDh = in_sizes[6];           // 512
    const int Hkv   = HkvDh / Dh;            // 4
    const int S     = in_sizes[1] / Dh;      // 1024
    const int B     = in_sizes[0] / (S * Dm);// 2
    const int M     = B * S;                 // 2048
    const int nrep  = H / Hkv;               // 4

    // workspace layout; Wqb/Wkb/Wvb contiguous => packed (HDh+2*HkvDh, Dm)
    char* ws = (char*)d_ws;
    short* hsb  = (short*)ws;  ws += (size_t)M * Dm      * 2;  // 8 MB
    short* Wqb  = (short*)ws;  ws += (size_t)HDh * Dm    * 2;  // 8 MB
    short* Wkb  = (short*)ws;  ws += (size_t)HkvDh * Dm  * 2;  // 2 MB
    short* Wvb  = (short*)ws;  ws += (size_t)HkvDh * Dm  * 2;  // 2 MB
    short* Wob  = (short*)ws;  ws += (size_t)Dm * HDh    * 2;  // 8 MB
    short* qg16 = (short*)ws;  ws += (size_t)M * HDh     * 2;  // 8 MB
    short* kg16 = (short*)ws;  ws += (size_t)M * HkvDh   * 2;  // 2 MB
    short* qbuf = (short*)ws;  ws += (size_t)M * HDh     * 2;  // 8 MB
    short* kbuf = (short*)ws;  ws += (size_t)M * HkvDh   * 2;  // 2 MB
    short* vbuf = (short*)ws;  ws += (size_t)M * HkvDh   * 2;  // 2 MB
    short* abuf = qg16;   // alias: q-gemm output dead after ln_rope

    dim3 blk(256);
    auto cvt = [&](const float* s, short* d, int n) {
        cvt_bf16<<<dim3((n / 4 + 255) / 256), blk, 0, stream>>>(s, d, n);
    };
    cvt(hs, hsb, M * Dm);
    cvt(Wq, Wqb, HDh * Dm);
    cvt(Wk, Wkb, HkvDh * Dm);
    cvt(Wv, Wvb, HkvDh * Dm);
    cvt(Wo, Wob, Dm * HDh);

    const int Ntot = HDh + 2 * HkvDh;  // 3072
    gemm128<0><<<dim3(Ntot / 128, M / 128), blk, 0, stream>>>(
        hsb, Wqb, bq, bk, bv, qg16, kg16, vbuf, nullptr,
        M, Dm, S, Hkv, HDh, HkvDh, Ntot);

    ln_rope<<<dim3(M * H / 4),   blk, 0, stream>>>(qg16, qbuf, qg, qb_, cosp, sinp, H,   S);
    ln_rope<<<dim3(M * Hkv / 4), blk, 0, stream>>>(kg16, kbuf, kg, kb_, cosp, sinp, Hkv, S);

    const float scale = 1.0f / sqrtf((float)Dh);
    attn<<<dim3(S / 64, H, B), blk, 0, stream>>>(qbuf, kbuf, vbuf, abuf, S, H, Hkv, nrep, scale);

    gemm128<1><<<dim3(Dm / 128, M / 128), blk, 0, stream>>>(
        abuf, Wob, bo, nullptr, nullptr, nullptr, nullptr, nullptr, (float*)d_out,
        M, HDh, S, Hkv, Dm, 0, Dm);
}

// Round 5
// 331.740 us; speedup vs baseline: 1.7134x; 1.1339x over previous
//
#include <hip/hip_runtime.h>
#include <cmath>

typedef __attribute__((ext_vector_type(8))) short bf16x8;
typedef __attribute__((ext_vector_type(4))) short s16x4;
typedef __attribute__((ext_vector_type(4))) float f32x4;

#define MFMA_BF16 __builtin_amdgcn_mfma_f32_16x16x32_bf16

__device__ __forceinline__ float bf2f(short s) {
    unsigned u = ((unsigned)(unsigned short)s) << 16;
    return __builtin_bit_cast(float, u);
}
__device__ __forceinline__ short f2bf(float f) {
    unsigned u = __builtin_bit_cast(unsigned, f);
    u += 0x7fffu + ((u >> 16) & 1u);   // RNE
    return (short)(u >> 16);
}

// Fused fp32->bf16 conversion for 5 tensors; every segment size is a
// multiple of 1024 so each 256-thread block (4 elems/thread) stays in one.
__global__ __launch_bounds__(256) void cvt5(
    const float* s0, short* d0, int n0,
    const float* s1, short* d1, int n1,
    const float* s2, short* d2, int n2,
    const float* s3, short* d3, int n3,
    const float* s4, short* d4, int n4)
{
    long long i = (long long)blockIdx.x * 1024 + threadIdx.x * 4;
    const float* s; short* d;
    if      (i < n0)                  { s = s0; d = d0; }
    else if ((i -= n0) < n1)          { s = s1; d = d1; }
    else if ((i -= n1) < n2)          { s = s2; d = d2; }
    else if ((i -= n2) < n3)          { s = s3; d = d3; }
    else      { i -= n3;                s = s4; d = d4; }
    float4 v = *(const float4*)(s + i);
    s16x4 o;
    o[0] = f2bf(v.x); o[1] = f2bf(v.y); o[2] = f2bf(v.z); o[3] = f2bf(v.w);
    *(s16x4*)(d + i) = o;
}

// Stage a 128x32 bf16 tile (8 KB) global row-major -> LDS [128][32] via
// global_load_lds width=16 (wave-uniform base + lane*16B, m104 caveat).
__device__ __forceinline__ void stage128x32(
    const short* __restrict__ g, int gstride, short* l,
    int w, int lane, int kofs)
{
    const int row0 = 32 * w + (lane >> 2);
    const int kq   = (lane & 3) * 8;
#pragma unroll
    for (int i = 0; i < 2; i++) {
        const short* gp = g + (size_t)(row0 + 16 * i) * gstride + kofs + kq;
        short* lp = l + (32 * w + 16 * i) * 32 + lane * 8;
        __builtin_amdgcn_global_load_lds(
            (const __attribute__((address_space(1))) unsigned int*)gp,
            (__attribute__((address_space(3))) unsigned int*)lp, 16, 0, 0);
    }
}

// 128x128-tile GEMM: C = A @ W^T (+bias). 4 waves 2x2, wave 64x64, BK=32,
// double-buffered LDS, global_load_lds staging.
// MODE 0: QKV fused epilogue; MODE 1: fp32 out + bias (bq).
template <int MODE>
__global__ __launch_bounds__(256) void gemm128(
    const short* __restrict__ A, const short* __restrict__ W,
    const float* __restrict__ bq, const float* __restrict__ bk,
    const float* __restrict__ bv,
    short* __restrict__ qo, short* __restrict__ ko, short* __restrict__ vo,
    float* __restrict__ fo,
    int M, int K, int S, int Hkv, int Nq, int Nkv, int N)
{
    __shared__ __align__(16) short As[2][128 * 32];
    __shared__ __align__(16) short Bs[2][128 * 32];

    const int w    = threadIdx.x >> 6;
    const int lane = threadIdx.x & 63;
    const int l15  = lane & 15;
    const int quad = lane >> 4;
    const int wy   = w >> 1;
    const int wx   = w & 1;
    const int m0   = blockIdx.y * 128;
    const int n0   = blockIdx.x * 128;

    f32x4 acc[4][4];
#pragma unroll
    for (int i = 0; i < 4; i++)
#pragma unroll
        for (int j = 0; j < 4; j++) acc[i][j] = f32x4{0.f, 0.f, 0.f, 0.f};

    const short* Ab = A + (size_t)m0 * K;
    const short* Wb = W + (size_t)n0 * K;

    const int nk = K / 32;
    stage128x32(Ab, K, As[0], w, lane, 0);
    stage128x32(Wb, K, Bs[0], w, lane, 0);
    __syncthreads();

    for (int kt = 0; kt < nk; kt++) {
        const int cur = kt & 1;
        if (kt + 1 < nk) {
            stage128x32(Ab, K, As[cur ^ 1], w, lane, (kt + 1) * 32);
            stage128x32(Wb, K, Bs[cur ^ 1], w, lane, (kt + 1) * 32);
        }
        bf16x8 af[4], bfr[4];
#pragma unroll
        for (int i = 0; i < 4; i++)
            af[i] = *(const bf16x8*)(As[cur] + (wy * 64 + i * 16 + l15) * 32 + quad * 8);
#pragma unroll
        for (int j = 0; j < 4; j++)
            bfr[j] = *(const bf16x8*)(Bs[cur] + (wx * 64 + j * 16 + l15) * 32 + quad * 8);
#pragma unroll
        for (int i = 0; i < 4; i++)
#pragma unroll
            for (int j = 0; j < 4; j++)
                acc[i][j] = MFMA_BF16(af[i], bfr[j], acc[i][j], 0, 0, 0);
        __syncthreads();
    }

#pragma unroll
    for (int i = 0; i < 4; i++) {
#pragma unroll
        for (int j = 0; j < 4; j++) {
            const int col = n0 + wx * 64 + j * 16 + l15;
#pragma unroll
            for (int r = 0; r < 4; r++) {
                const int row = m0 + wy * 64 + i * 16 + quad * 4 + r;
                float v = acc[i][j][r];
                if constexpr (MODE == 0) {
                    if (col < Nq) {
                        qo[(size_t)row * Nq + col] = f2bf(v + bq[col]);
                    } else if (col < Nq + Nkv) {
                        int cn = col - Nq;
                        ko[(size_t)row * Nkv + cn] = f2bf(v + bk[cn]);
                    } else {
                        int cn = col - Nq - Nkv;
                        int b  = row / S, s = row - b * S;
                        int hk = cn >> 7, dh = cn & 127;   // Dh == 128
                        vo[(size_t)((b * Hkv + hk) * 128 + dh) * S + s] = f2bf(v + bv[cn]);
                    }
                } else {
                    fo[(size_t)row * N + col] = v + bq[col];
                }
            }
        }
    }
}

// Per-(token, head) LayerNorm over Dh=128 then RoPE. One wave per row-head.
__global__ __launch_bounds__(256) void ln_rope(
    const short* __restrict__ X, short* __restrict__ Y,
    const float* __restrict__ g, const float* __restrict__ bta,
    const float* __restrict__ cosp, const float* __restrict__ sinp,
    int H, int S)
{
    const int gw   = blockIdx.x * 4 + (threadIdx.x >> 6);
    const int lane = threadIdx.x & 63;
    const int h  = gw % H;
    const int rs = gw / H;          // b*S + s
    const int b  = rs / S;
    const int s  = rs - b * S;

    const short* x = X + ((size_t)rs * H + h) * 128;
    float x0 = bf2f(x[lane]), x1 = bf2f(x[lane + 64]);

    float sum = x0 + x1;
    float sq  = x0 * x0 + x1 * x1;
#pragma unroll
    for (int off = 32; off > 0; off >>= 1) {
        sum += __shfl_xor(sum, off, 64);
        sq  += __shfl_xor(sq, off, 64);
    }
    float mu  = sum * (1.f / 128.f);
    float var = sq * (1.f / 128.f) - mu * mu;
    float rinv = rsqrtf(var + 1e-5f);

    float y0 = (x0 - mu) * rinv * g[lane]      + bta[lane];
    float y1 = (x1 - mu) * rinv * g[lane + 64] + bta[lane + 64];

    float c0 = cosp[(size_t)s * 128 + lane];
    float c1 = cosp[(size_t)s * 128 + lane + 64];
    float s0 = sinp[(size_t)s * 128 + lane];
    float s1 = sinp[(size_t)s * 128 + lane + 64];

    float o0 = y0 * c0 - y1 * s0;
    float o1 = y1 * c1 + y0 * s1;

    short* yp = Y + ((size_t)(b * H + h) * S + s) * 128;
    yp[lane]      = f2bf(o0);
    yp[lane + 64] = f2bf(o1);
}

// Flash attention, barrier-free. Q: bf16 (B,H,S,128). Kt: (B,Hkv,S,128).
// Vt: (B,Hkv,128,S). O: bf16 (B,S,H*128).
// Grid: x = b*H+h (XCD swizzle: same (b,h) -> ids 32 apart -> same XCD),
//       y = q-tile (reversed so 16-tile blocks dispatch first).
// One wave = 16 q-rows, 64-key tiles, all 32 K/V frags loaded up-front
// (needs the 256-VGPR budget from __launch_bounds__(256,2); grid caps
// occupancy at 8 waves/CU anyway so nothing is lost).
__global__ __launch_bounds__(256, 2) void attn(
    const short* __restrict__ Q, const short* __restrict__ Kt,
    const short* __restrict__ Vt, short* __restrict__ O,
    int S, int H, int Hkv, int nrep, float scale)
{
    __shared__ __align__(16) short P[4][16][72];

    const int w    = threadIdx.x >> 6;
    const int lane = threadIdx.x & 63;
    const int l15  = lane & 15;
    const int quad = lane >> 4;
    const int bh   = blockIdx.x;
    const int h    = bh % H;
    const int b    = bh / H;
    const int qblk = (gridDim.y - 1) - blockIdx.y;   // LPT: big blocks first
    const int hk   = h / nrep;
    const int m0   = qblk * 64 + w * 16;

    const short* qb = Q  + (size_t)(b * H + h) * S * 128;
    const short* kb = Kt + (size_t)(b * Hkv + hk) * S * 128;
    const short* vb = Vt + (size_t)(b * Hkv + hk) * 128 * S;

    bf16x8 qf[4];
#pragma unroll
    for (int c = 0; c < 4; c++)
        qf[c] = *(const bf16x8*)(qb + (size_t)(m0 + l15) * 128 + c * 32 + quad * 8);

    f32x4 of[8];
#pragma unroll
    for (int c = 0; c < 8; c++) of[c] = f32x4{0.f, 0.f, 0.f, 0.f};
    float m_r[4], l_r[4];
#pragma unroll
    for (int r = 0; r < 4; r++) { m_r[r] = -1e30f; l_r[r] = 0.f; }

    const int nkt = qblk + 1;
    for (int kt = 0; kt < nkt; kt++) {
        const int j0 = kt * 64;

        // Load ALL K and V fragments for this tile up front: one latency
        // exposure; V latency hides behind QK-MFMA + softmax.
        bf16x8 kf[4][4];   // [t][c]
#pragma unroll
        for (int t = 0; t < 4; t++)
#pragma unroll
            for (int c = 0; c < 4; c++)
                kf[t][c] = *(const bf16x8*)(kb + (size_t)(j0 + t * 16 + l15) * 128 + c * 32 + quad * 8);
        bf16x8 vf[8][2];   // [c][half]
#pragma unroll
        for (int c = 0; c < 8; c++) {
            vf[c][0] = *(const bf16x8*)(vb + (size_t)(c * 16 + l15) * S + j0 + quad * 8);
            vf[c][1] = *(const bf16x8*)(vb + (size_t)(c * 16 + l15) * S + j0 + 32 + quad * 8);
        }

        f32x4 sc[4];
#pragma unroll
        for (int t = 0; t < 4; t++) sc[t] = f32x4{0.f, 0.f, 0.f, 0.f};
#pragma unroll
        for (int c = 0; c < 4; c++)
#pragma unroll
            for (int t = 0; t < 4; t++)
                sc[t] = MFMA_BF16(qf[c], kf[t][c], sc[t], 0, 0, 0);

        float p[4][4], alpha[4];
#pragma unroll
        for (int r = 0; r < 4; r++) {
            const int qpos = m0 + quad * 4 + r;
            float v[4];
#pragma unroll
            for (int t = 0; t < 4; t++) {
                v[t] = sc[t][r] * scale;
                if (j0 + t * 16 + l15 > qpos) v[t] = -1e30f;
            }
            float mx = fmaxf(fmaxf(v[0], v[1]), fmaxf(v[2], v[3]));
            mx = fmaxf(mx, __shfl_xor(mx, 1, 64));
            mx = fmaxf(mx, __shfl_xor(mx, 2, 64));
            mx = fmaxf(mx, __shfl_xor(mx, 4, 64));
            mx = fmaxf(mx, __shfl_xor(mx, 8, 64));
            float mnew = fmaxf(m_r[r], mx);
            alpha[r] = __expf(m_r[r] - mnew);
            float sum = 0.f;
#pragma unroll
            for (int t = 0; t < 4; t++) {
                p[t][r] = __expf(v[t] - mnew);
                sum += p[t][r];
            }
            sum += __shfl_xor(sum, 1, 64);
            sum += __shfl_xor(sum, 2, 64);
            sum += __shfl_xor(sum, 4, 64);
            sum += __shfl_xor(sum, 8, 64);
            l_r[r] = l_r[r] * alpha[r] + sum;
            m_r[r] = mnew;
        }

#pragma unroll
        for (int c = 0; c < 8; c++) {
            f32x4 t = of[c];
            t[0] *= alpha[0]; t[1] *= alpha[1]; t[2] *= alpha[2]; t[3] *= alpha[3];
            of[c] = t;
        }

        // P (C-layout) -> wave-private LDS -> A-layout fragments; no barrier
#pragma unroll
        for (int r = 0; r < 4; r++)
#pragma unroll
            for (int t = 0; t < 4; t++)
                P[w][quad * 4 + r][t * 16 + l15] = f2bf(p[t][r]);
        bf16x8 pa0 = *(const bf16x8*)(&P[w][l15][quad * 8]);
        bf16x8 pa1 = *(const bf16x8*)(&P[w][l15][32 + quad * 8]);

#pragma unroll
        for (int c = 0; c < 8; c++) {
            of[c] = MFMA_BF16(pa0, vf[c][0], of[c], 0, 0, 0);
            of[c] = MFMA_BF16(pa1, vf[c][1], of[c], 0, 0, 0);
        }
    }

    const int HDh = H * 128;
    float rinv[4];
#pragma unroll
    for (int r = 0; r < 4; r++) rinv[r] = 1.0f / l_r[r];
#pragma unroll
    for (int c = 0; c < 8; c++)
#pragma unroll
        for (int r = 0; r < 4; r++) {
            int row = m0 + quad * 4 + r;
            O[((size_t)b * S + row) * HDh + h * 128 + c * 16 + l15] = f2bf(of[c][r] * rinv[r]);
        }
}

extern "C" void kernel_launch(void* const* d_in, const int* in_sizes, int n_in,
                              void* d_out, int out_size, void* d_ws, size_t ws_size,
                              hipStream_t stream) {
    const float* hs   = (const float*)d_in[0];
    const float* cosp = (const float*)d_in[1];
    const float* sinp = (const float*)d_in[2];
    const float* Wq   = (const float*)d_in[3];
    const float* bq   = (const float*)d_in[4];
    const float* Wk   = (const float*)d_in[5];
    const float* bk   = (const float*)d_in[6];
    const float* Wv   = (const float*)d_in[7];
    const float* bv   = (const float*)d_in[8];
    const float* Wo   = (const float*)d_in[9];
    const float* bo   = (const float*)d_in[10];
    const float* qg   = (const float*)d_in[11];
    const float* qb_  = (const float*)d_in[12];
    const float* kg   = (const float*)d_in[13];
    const float* kb_  = (const float*)d_in[14];

    const int Dh    = in_sizes[11];          // 128
    const int Dm    = in_sizes[10];          // 2048
    const int HDh   = in_sizes[4];           // 2048
    const int H     = HDh / Dh;              // 16
    const int HkvDh = in_sizes[6];           // 512
    const int Hkv   = HkvDh / Dh;            // 4
    const int S     = in_sizes[1] / Dh;      // 1024
    const int B     = in_sizes[0] / (S * Dm);// 2
    const int M     = B * S;                 // 2048
    const int nrep  = H / Hkv;               // 4

    // workspace layout; Wqb/Wkb/Wvb contiguous => packed (HDh+2*HkvDh, Dm)
    char* ws = (char*)d_ws;
    short* hsb  = (short*)ws;  ws += (size_t)M * Dm      * 2;  // 8 MB
    short* Wqb  = (short*)ws;  ws += (size_t)HDh * Dm    * 2;  // 8 MB
    short* Wkb  = (short*)ws;  ws += (size_t)HkvDh * Dm  * 2;  // 2 MB
    short* Wvb  = (short*)ws;  ws += (size_t)HkvDh * Dm  * 2;  // 2 MB
    short* Wob  = (short*)ws;  ws += (size_t)Dm * HDh    * 2;  // 8 MB
    short* qg16 = (short*)ws;  ws += (size_t)M * HDh     * 2;  // 8 MB
    short* kg16 = (short*)ws;  ws += (size_t)M * HkvDh   * 2;  // 2 MB
    short* qbuf = (short*)ws;  ws += (size_t)M * HDh     * 2;  // 8 MB
    short* kbuf = (short*)ws;  ws += (size_t)M * HkvDh   * 2;  // 2 MB
    short* vbuf = (short*)ws;  ws += (size_t)M * HkvDh   * 2;  // 2 MB
    short* abuf = qg16;   // alias: q-gemm output dead after ln_rope

    dim3 blk(256);
    const int n0 = M * Dm, n1 = HDh * Dm, n2 = HkvDh * Dm, n3 = HkvDh * Dm, n4 = Dm * HDh;
    cvt5<<<dim3((n0 + n1 + n2 + n3 + n4) / 1024), blk, 0, stream>>>(
        hs, hsb, n0, Wq, Wqb, n1, Wk, Wkb, n2, Wv, Wvb, n3, Wo, Wob, n4);

    const int Ntot = HDh + 2 * HkvDh;  // 3072
    gemm128<0><<<dim3(Ntot / 128, M / 128), blk, 0, stream>>>(
        hsb, Wqb, bq, bk, bv, qg16, kg16, vbuf, nullptr,
        M, Dm, S, Hkv, HDh, HkvDh, Ntot);

    ln_rope<<<dim3(M * H / 4),   blk, 0, stream>>>(qg16, qbuf, qg, qb_, cosp, sinp, H,   S);
    ln_rope<<<dim3(M * Hkv / 4), blk, 0, stream>>>(kg16, kbuf, kg, kb_, cosp, sinp, Hkv, S);

    const float scale = 1.0f / sqrtf((float)Dh);
    attn<<<dim3(H * B, S / 64), blk, 0, stream>>>(qbuf, kbuf, vbuf, abuf, S, H, Hkv, nrep, scale);

    gemm128<1><<<dim3(Dm / 128, M / 128), blk, 0, stream>>>(
        abuf, Wob, bo, nullptr, nullptr, nullptr, nullptr, nullptr, (float*)d_out,
        M, HDh, S, Hkv, Dm, 0, Dm);
}

// Round 6
// 329.461 us; speedup vs baseline: 1.7253x; 1.0069x over previous
//
#include <hip/hip_runtime.h>
#include <cmath>

typedef __attribute__((ext_vector_type(8))) short bf16x8;
typedef __attribute__((ext_vector_type(4))) short s16x4;
typedef __attribute__((ext_vector_type(4))) float f32x4;

#define MFMA_BF16 __builtin_amdgcn_mfma_f32_16x16x32_bf16

__device__ __forceinline__ float bf2f(short s) {
    unsigned u = ((unsigned)(unsigned short)s) << 16;
    return __builtin_bit_cast(float, u);
}
__device__ __forceinline__ short f2bf(float f) {
    unsigned u = __builtin_bit_cast(unsigned, f);
    u += 0x7fffu + ((u >> 16) & 1u);   // RNE
    return (short)(u >> 16);
}

// Fused fp32->bf16 conversion for 5 tensors; every segment size is a
// multiple of 1024 so each 256-thread block (4 elems/thread) stays in one.
__global__ __launch_bounds__(256) void cvt5(
    const float* s0, short* d0, int n0,
    const float* s1, short* d1, int n1,
    const float* s2, short* d2, int n2,
    const float* s3, short* d3, int n3,
    const float* s4, short* d4, int n4)
{
    long long i = (long long)blockIdx.x * 1024 + threadIdx.x * 4;
    const float* s; short* d;
    if      (i < n0)                  { s = s0; d = d0; }
    else if ((i -= n0) < n1)          { s = s1; d = d1; }
    else if ((i -= n1) < n2)          { s = s2; d = d2; }
    else if ((i -= n2) < n3)          { s = s3; d = d3; }
    else      { i -= n3;                s = s4; d = d4; }
    float4 v = *(const float4*)(s + i);
    s16x4 o;
    o[0] = f2bf(v.x); o[1] = f2bf(v.y); o[2] = f2bf(v.z); o[3] = f2bf(v.w);
    *(s16x4*)(d + i) = o;
}

// Stage a 128x32 bf16 tile (8 KB) global row-major -> LDS [128][32] via
// global_load_lds width=16 (wave-uniform base + lane*16B, m104 caveat).
__device__ __forceinline__ void stage128x32(
    const short* __restrict__ g, int gstride, short* l,
    int w, int lane, int kofs)
{
    const int row0 = 32 * w + (lane >> 2);
    const int kq   = (lane & 3) * 8;
#pragma unroll
    for (int i = 0; i < 2; i++) {
        const short* gp = g + (size_t)(row0 + 16 * i) * gstride + kofs + kq;
        short* lp = l + (32 * w + 16 * i) * 32 + lane * 8;
        __builtin_amdgcn_global_load_lds(
            (const __attribute__((address_space(1))) unsigned int*)gp,
            (__attribute__((address_space(3))) unsigned int*)lp, 16, 0, 0);
    }
}

// 128x128-tile GEMM: C = A @ W^T (+bias). 4 waves 2x2, wave 64x64, BK=32,
// double-buffered LDS, global_load_lds staging.
// MODE 0: QKV fused epilogue; MODE 1: fp32 out + bias (bq).
template <int MODE>
__global__ __launch_bounds__(256) void gemm128(
    const short* __restrict__ A, const short* __restrict__ W,
    const float* __restrict__ bq, const float* __restrict__ bk,
    const float* __restrict__ bv,
    short* __restrict__ qo, short* __restrict__ ko, short* __restrict__ vo,
    float* __restrict__ fo,
    int M, int K, int S, int Hkv, int Nq, int Nkv, int N)
{
    __shared__ __align__(16) short As[2][128 * 32];
    __shared__ __align__(16) short Bs[2][128 * 32];

    const int w    = threadIdx.x >> 6;
    const int lane = threadIdx.x & 63;
    const int l15  = lane & 15;
    const int quad = lane >> 4;
    const int wy   = w >> 1;
    const int wx   = w & 1;
    const int m0   = blockIdx.y * 128;
    const int n0   = blockIdx.x * 128;

    f32x4 acc[4][4];
#pragma unroll
    for (int i = 0; i < 4; i++)
#pragma unroll
        for (int j = 0; j < 4; j++) acc[i][j] = f32x4{0.f, 0.f, 0.f, 0.f};

    const short* Ab = A + (size_t)m0 * K;
    const short* Wb = W + (size_t)n0 * K;

    const int nk = K / 32;
    stage128x32(Ab, K, As[0], w, lane, 0);
    stage128x32(Wb, K, Bs[0], w, lane, 0);
    __syncthreads();

    for (int kt = 0; kt < nk; kt++) {
        const int cur = kt & 1;
        if (kt + 1 < nk) {
            stage128x32(Ab, K, As[cur ^ 1], w, lane, (kt + 1) * 32);
            stage128x32(Wb, K, Bs[cur ^ 1], w, lane, (kt + 1) * 32);
        }
        bf16x8 af[4], bfr[4];
#pragma unroll
        for (int i = 0; i < 4; i++)
            af[i] = *(const bf16x8*)(As[cur] + (wy * 64 + i * 16 + l15) * 32 + quad * 8);
#pragma unroll
        for (int j = 0; j < 4; j++)
            bfr[j] = *(const bf16x8*)(Bs[cur] + (wx * 64 + j * 16 + l15) * 32 + quad * 8);
#pragma unroll
        for (int i = 0; i < 4; i++)
#pragma unroll
            for (int j = 0; j < 4; j++)
                acc[i][j] = MFMA_BF16(af[i], bfr[j], acc[i][j], 0, 0, 0);
        __syncthreads();
    }

#pragma unroll
    for (int i = 0; i < 4; i++) {
#pragma unroll
        for (int j = 0; j < 4; j++) {
            const int col = n0 + wx * 64 + j * 16 + l15;
#pragma unroll
            for (int r = 0; r < 4; r++) {
                const int row = m0 + wy * 64 + i * 16 + quad * 4 + r;
                float v = acc[i][j][r];
                if constexpr (MODE == 0) {
                    if (col < Nq) {
                        qo[(size_t)row * Nq + col] = f2bf(v + bq[col]);
                    } else if (col < Nq + Nkv) {
                        int cn = col - Nq;
                        ko[(size_t)row * Nkv + cn] = f2bf(v + bk[cn]);
                    } else {
                        int cn = col - Nq - Nkv;
                        int b  = row / S, s = row - b * S;
                        int hk = cn >> 7, dh = cn & 127;   // Dh == 128
                        vo[(size_t)((b * Hkv + hk) * 128 + dh) * S + s] = f2bf(v + bv[cn]);
                    }
                } else {
                    fo[(size_t)row * N + col] = v + bq[col];
                }
            }
        }
    }
}

// Per-(token, head) LayerNorm over Dh=128 then RoPE. One wave per row-head.
__global__ __launch_bounds__(256) void ln_rope(
    const short* __restrict__ X, short* __restrict__ Y,
    const float* __restrict__ g, const float* __restrict__ bta,
    const float* __restrict__ cosp, const float* __restrict__ sinp,
    int H, int S)
{
    const int gw   = blockIdx.x * 4 + (threadIdx.x >> 6);
    const int lane = threadIdx.x & 63;
    const int h  = gw % H;
    const int rs = gw / H;          // b*S + s
    const int b  = rs / S;
    const int s  = rs - b * S;

    const short* x = X + ((size_t)rs * H + h) * 128;
    float x0 = bf2f(x[lane]), x1 = bf2f(x[lane + 64]);

    float sum = x0 + x1;
    float sq  = x0 * x0 + x1 * x1;
#pragma unroll
    for (int off = 32; off > 0; off >>= 1) {
        sum += __shfl_xor(sum, off, 64);
        sq  += __shfl_xor(sq, off, 64);
    }
    float mu  = sum * (1.f / 128.f);
    float var = sq * (1.f / 128.f) - mu * mu;
    float rinv = rsqrtf(var + 1e-5f);

    float y0 = (x0 - mu) * rinv * g[lane]      + bta[lane];
    float y1 = (x1 - mu) * rinv * g[lane + 64] + bta[lane + 64];

    float c0 = cosp[(size_t)s * 128 + lane];
    float c1 = cosp[(size_t)s * 128 + lane + 64];
    float s0 = sinp[(size_t)s * 128 + lane];
    float s1 = sinp[(size_t)s * 128 + lane + 64];

    float o0 = y0 * c0 - y1 * s0;
    float o1 = y1 * c1 + y0 * s1;

    short* yp = Y + ((size_t)(b * H + h) * S + s) * 128;
    yp[lane]      = f2bf(o0);
    yp[lane + 64] = f2bf(o1);
}

// Flash attention, transposed-score formulation. Q: bf16 (B,H,S,128).
// Kt: (B,Hkv,S,128). Vt: (B,Hkv,128,S). O: bf16 (B,S,H*128).
// Scores computed as D[key][query] = MFMA(K_frag, Q_frag): query = lane (l15),
// key = in-register (t*16 + quad*4 + r). Softmax state (m, l, alpha) is one
// scalar per lane; reduction over keys = in-lane tree + 2 butterfly shuffles.
// PV also transposed: of = MFMA(V_as_A, P_as_B) -> D[dh][query], so the
// alpha rescale is a per-lane scalar multiply. All global loads identical to
// the non-transposed version (A/B fragment in-lane layouts are symmetric).
// Grid: x = b*H+h (XCD swizzle), y -> zigzag q-tile (balanced pairs y,y+8).
__global__ __launch_bounds__(256, 2) void attn(
    const short* __restrict__ Q, const short* __restrict__ Kt,
    const short* __restrict__ Vt, short* __restrict__ O,
    int S, int H, int Hkv, int nrep, float scale)
{
    __shared__ __align__(16) short P[4][16][72];

    const int w    = threadIdx.x >> 6;
    const int lane = threadIdx.x & 63;
    const int l15  = lane & 15;
    const int quad = lane >> 4;
    const int bh   = blockIdx.x;
    const int h    = bh % H;
    const int b    = bh / H;
    const int nyt  = gridDim.y;
    const int y    = blockIdx.y;
    // zigzag: pairs (y, y+nyt/2) get qblk summing to nyt-1 -> balanced per CU
    const int qblk = (y < (nyt >> 1)) ? (nyt - 1 - y) : (y - (nyt >> 1));
    const int hk   = h / nrep;
    const int m0   = qblk * 64 + w * 16;
    const int qpos = m0 + l15;          // this lane's query row

    const short* qb = Q  + (size_t)(b * H + h) * S * 128;
    const short* kb = Kt + (size_t)(b * Hkv + hk) * S * 128;
    const short* vb = Vt + (size_t)(b * Hkv + hk) * 128 * S;

    bf16x8 qf[4];
#pragma unroll
    for (int c = 0; c < 4; c++)
        qf[c] = *(const bf16x8*)(qb + (size_t)(m0 + l15) * 128 + c * 32 + quad * 8);

    f32x4 of[8];     // D[dh][query]: r -> dh sub-index, lane l15 -> query
#pragma unroll
    for (int c = 0; c < 8; c++) of[c] = f32x4{0.f, 0.f, 0.f, 0.f};
    float m_s = -1e30f, l_s = 0.f;   // per-lane (per-query) softmax state

    const int nkt = qblk + 1;
    for (int kt = 0; kt < nkt; kt++) {
        const int j0 = kt * 64;

        bf16x8 kf[4][4];   // [t][c]
#pragma unroll
        for (int t = 0; t < 4; t++)
#pragma unroll
            for (int c = 0; c < 4; c++)
                kf[t][c] = *(const bf16x8*)(kb + (size_t)(j0 + t * 16 + l15) * 128 + c * 32 + quad * 8);
        bf16x8 vf[8][2];   // [c][half]
#pragma unroll
        for (int c = 0; c < 8; c++) {
            vf[c][0] = *(const bf16x8*)(vb + (size_t)(c * 16 + l15) * S + j0 + quad * 8);
            vf[c][1] = *(const bf16x8*)(vb + (size_t)(c * 16 + l15) * S + j0 + 32 + quad * 8);
        }

        // sc[t] = D[key][query] for keys j0 + t*16 + quad*4 + r, query = qpos
        f32x4 sc[4];
#pragma unroll
        for (int t = 0; t < 4; t++) sc[t] = f32x4{0.f, 0.f, 0.f, 0.f};
#pragma unroll
        for (int c = 0; c < 4; c++)
#pragma unroll
            for (int t = 0; t < 4; t++)
                sc[t] = MFMA_BF16(kf[t][c], qf[c], sc[t], 0, 0, 0);

        // mask + scale, in-lane over 16 key values
        float v[4][4];
        float mx = -1e30f;
#pragma unroll
        for (int t = 0; t < 4; t++)
#pragma unroll
            for (int r = 0; r < 4; r++) {
                float s_ = sc[t][r] * scale;
                if (j0 + t * 16 + quad * 4 + r > qpos) s_ = -1e30f;
                v[t][r] = s_;
                mx = fmaxf(mx, s_);
            }
        // butterfly over quads only (query fixed per l15 group)
        mx = fmaxf(mx, __shfl_xor(mx, 16, 64));
        mx = fmaxf(mx, __shfl_xor(mx, 32, 64));
        float mnew  = fmaxf(m_s, mx);
        float alpha = __expf(m_s - mnew);
        float sum = 0.f;
        float p[4][4];
#pragma unroll
        for (int t = 0; t < 4; t++)
#pragma unroll
            for (int r = 0; r < 4; r++) {
                p[t][r] = __expf(v[t][r] - mnew);
                sum += p[t][r];
            }
        sum += __shfl_xor(sum, 16, 64);
        sum += __shfl_xor(sum, 32, 64);
        l_s = l_s * alpha + sum;
        m_s = mnew;

#pragma unroll
        for (int c = 0; c < 8; c++) {
            f32x4 t = of[c];
            t[0] *= alpha; t[1] *= alpha; t[2] *= alpha; t[3] *= alpha;
            of[c] = t;
        }

        // P[key][query] -> LDS rows = query(l15), 4 consecutive keys per b64
#pragma unroll
        for (int t = 0; t < 4; t++) {
            s16x4 pk;
#pragma unroll
            for (int r = 0; r < 4; r++) pk[r] = f2bf(p[t][r]);
            *(s16x4*)(&P[w][l15][t * 16 + quad * 4]) = pk;
        }
        // B-operand fragment: lane l15 = query, keys = c32*32 + quad*8 + j
        bf16x8 pb0 = *(const bf16x8*)(&P[w][l15][quad * 8]);
        bf16x8 pb1 = *(const bf16x8*)(&P[w][l15][32 + quad * 8]);

#pragma unroll
        for (int c = 0; c < 8; c++) {
            of[c] = MFMA_BF16(vf[c][0], pb0, of[c], 0, 0, 0);
            of[c] = MFMA_BF16(vf[c][1], pb1, of[c], 0, 0, 0);
        }
    }

    const int HDh = H * 128;
    const float rinv = 1.0f / l_s;
    // of[c][r] = O[dh = c*16 + quad*4 + r][query = qpos]; pack 4 dh per store
    short* orow = O + ((size_t)b * S + qpos) * HDh + h * 128;
#pragma unroll
    for (int c = 0; c < 8; c++) {
        s16x4 ov;
#pragma unroll
        for (int r = 0; r < 4; r++) ov[r] = f2bf(of[c][r] * rinv);
        *(s16x4*)(orow + c * 16 + quad * 4) = ov;
    }
}

extern "C" void kernel_launch(void* const* d_in, const int* in_sizes, int n_in,
                              void* d_out, int out_size, void* d_ws, size_t ws_size,
                              hipStream_t stream) {
    const float* hs   = (const float*)d_in[0];
    const float* cosp = (const float*)d_in[1];
    const float* sinp = (const float*)d_in[2];
    const float* Wq   = (const float*)d_in[3];
    const float* bq   = (const float*)d_in[4];
    const float* Wk   = (const float*)d_in[5];
    const float* bk   = (const float*)d_in[6];
    const float* Wv   = (const float*)d_in[7];
    const float* bv   = (const float*)d_in[8];
    const float* Wo   = (const float*)d_in[9];
    const float* bo   = (const float*)d_in[10];
    const float* qg   = (const float*)d_in[11];
    const float* qb_  = (const float*)d_in[12];
    const float* kg   = (const float*)d_in[13];
    const float* kb_  = (const float*)d_in[14];

    const int Dh    = in_sizes[11];          // 128
    const int Dm    = in_sizes[10];          // 2048
    const int HDh   = in_sizes[4];           // 2048
    const int H     = HDh / Dh;              // 16
    const int HkvDh = in_sizes[6];           // 512
    const int Hkv   = HkvDh / Dh;            // 4
    const int S     = in_sizes[1] / Dh;      // 1024
    const int B     = in_sizes[0] / (S * Dm);// 2
    const int M     = B * S;                 // 2048
    const int nrep  = H / Hkv;               // 4

    // workspace layout; Wqb/Wkb/Wvb contiguous => packed (HDh+2*HkvDh, Dm)
    char* ws = (char*)d_ws;
    short* hsb  = (short*)ws;  ws += (size_t)M * Dm      * 2;  // 8 MB
    short* Wqb  = (short*)ws;  ws += (size_t)HDh * Dm    * 2;  // 8 MB
    short* Wkb  = (short*)ws;  ws += (size_t)HkvDh * Dm  * 2;  // 2 MB
    short* Wvb  = (short*)ws;  ws += (size_t)HkvDh * Dm  * 2;  // 2 MB
    short* Wob  = (short*)ws;  ws += (size_t)Dm * HDh    * 2;  // 8 MB
    short* qg16 = (short*)ws;  ws += (size_t)M * HDh     * 2;  // 8 MB
    short* kg16 = (short*)ws;  ws += (size_t)M * HkvDh   * 2;  // 2 MB
    short* qbuf = (short*)ws;  ws += (size_t)M * HDh     * 2;  // 8 MB
    short* kbuf = (short*)ws;  ws += (size_t)M * HkvDh   * 2;  // 2 MB
    short* vbuf = (short*)ws;  ws += (size_t)M * HkvDh   * 2;  // 2 MB
    short* abuf = qg16;   // alias: q-gemm output dead after ln_rope

    dim3 blk(256);
    const int n0 = M * Dm, n1 = HDh * Dm, n2 = HkvDh * Dm, n3 = HkvDh * Dm, n4 = Dm * HDh;
    cvt5<<<dim3((n0 + n1 + n2 + n3 + n4) / 1024), blk, 0, stream>>>(
        hs, hsb, n0, Wq, Wqb, n1, Wk, Wkb, n2, Wv, Wvb, n3, Wo, Wob, n4);

    const int Ntot = HDh + 2 * HkvDh;  // 3072
    gemm128<0><<<dim3(Ntot / 128, M / 128), blk, 0, stream>>>(
        hsb, Wqb, bq, bk, bv, qg16, kg16, vbuf, nullptr,
        M, Dm, S, Hkv, HDh, HkvDh, Ntot);

    ln_rope<<<dim3(M * H / 4),   blk, 0, stream>>>(qg16, qbuf, qg, qb_, cosp, sinp, H,   S);
    ln_rope<<<dim3(M * Hkv / 4), blk, 0, stream>>>(kg16, kbuf, kg, kb_, cosp, sinp, Hkv, S);

    const float scale = 1.0f / sqrtf((float)Dh);
    attn<<<dim3(H * B, S / 64), blk, 0, stream>>>(qbuf, kbuf, vbuf, abuf, S, H, Hkv, nrep, scale);

    gemm128<1><<<dim3(Dm / 128, M / 128), blk, 0, stream>>>(
        abuf, Wob, bo, nullptr, nullptr, nullptr, nullptr, nullptr, (float*)d_out,
        M, HDh, S, Hkv, Dm, 0, Dm);
}

// Round 7
// 270.578 us; speedup vs baseline: 2.1007x; 1.2176x over previous
//
#include <hip/hip_runtime.h>
#include <cmath>

typedef __attribute__((ext_vector_type(8))) short bf16x8;
typedef __attribute__((ext_vector_type(4))) short s16x4;
typedef __attribute__((ext_vector_type(4))) float f32x4;

#define MFMA_BF16 __builtin_amdgcn_mfma_f32_16x16x32_bf16

__device__ __forceinline__ float bf2f(short s) {
    unsigned u = ((unsigned)(unsigned short)s) << 16;
    return __builtin_bit_cast(float, u);
}
__device__ __forceinline__ short f2bf(float f) {
    unsigned u = __builtin_bit_cast(unsigned, f);
    u += 0x7fffu + ((u >> 16) & 1u);   // RNE
    return (short)(u >> 16);
}

__device__ __forceinline__ void gl_lds16(const short* gp, short* lp) {
    __builtin_amdgcn_global_load_lds(
        (const __attribute__((address_space(1))) unsigned int*)gp,
        (__attribute__((address_space(3))) unsigned int*)lp, 16, 0, 0);
}

// Fused fp32->bf16 conversion for 5 tensors; every segment size is a
// multiple of 1024 so each 256-thread block (4 elems/thread) stays in one.
__global__ __launch_bounds__(256) void cvt5(
    const float* s0, short* d0, int n0,
    const float* s1, short* d1, int n1,
    const float* s2, short* d2, int n2,
    const float* s3, short* d3, int n3,
    const float* s4, short* d4, int n4)
{
    long long i = (long long)blockIdx.x * 1024 + threadIdx.x * 4;
    const float* s; short* d;
    if      (i < n0)                  { s = s0; d = d0; }
    else if ((i -= n0) < n1)          { s = s1; d = d1; }
    else if ((i -= n1) < n2)          { s = s2; d = d2; }
    else if ((i -= n2) < n3)          { s = s3; d = d3; }
    else      { i -= n3;                s = s4; d = d4; }
    float4 v = *(const float4*)(s + i);
    s16x4 o;
    o[0] = f2bf(v.x); o[1] = f2bf(v.y); o[2] = f2bf(v.z); o[3] = f2bf(v.w);
    *(s16x4*)(d + i) = o;
}

// Stage a 128x32 bf16 tile (8 KB) global row-major -> LDS [128][32] via
// global_load_lds width=16 (wave-uniform base + lane*16B, m104 caveat).
__device__ __forceinline__ void stage128x32(
    const short* __restrict__ g, int gstride, short* l,
    int w, int lane, int kofs)
{
    const int row0 = 32 * w + (lane >> 2);
    const int kq   = (lane & 3) * 8;
#pragma unroll
    for (int i = 0; i < 2; i++) {
        const short* gp = g + (size_t)(row0 + 16 * i) * gstride + kofs + kq;
        short* lp = l + (32 * w + 16 * i) * 32 + lane * 8;
        gl_lds16(gp, lp);
    }
}

// 128x128-tile GEMM: C = A @ W^T (+bias). 4 waves 2x2, wave 64x64, BK=32,
// double-buffered LDS, global_load_lds staging.
// MODE 0: QKV fused epilogue; MODE 1: fp32 out + bias (bq).
template <int MODE>
__global__ __launch_bounds__(256) void gemm128(
    const short* __restrict__ A, const short* __restrict__ W,
    const float* __restrict__ bq, const float* __restrict__ bk,
    const float* __restrict__ bv,
    short* __restrict__ qo, short* __restrict__ ko, short* __restrict__ vo,
    float* __restrict__ fo,
    int M, int K, int S, int Hkv, int Nq, int Nkv, int N)
{
    __shared__ __align__(16) short As[2][128 * 32];
    __shared__ __align__(16) short Bs[2][128 * 32];

    const int w    = threadIdx.x >> 6;
    const int lane = threadIdx.x & 63;
    const int l15  = lane & 15;
    const int quad = lane >> 4;
    const int wy   = w >> 1;
    const int wx   = w & 1;
    const int m0   = blockIdx.y * 128;
    const int n0   = blockIdx.x * 128;

    f32x4 acc[4][4];
#pragma unroll
    for (int i = 0; i < 4; i++)
#pragma unroll
        for (int j = 0; j < 4; j++) acc[i][j] = f32x4{0.f, 0.f, 0.f, 0.f};

    const short* Ab = A + (size_t)m0 * K;
    const short* Wb = W + (size_t)n0 * K;

    const int nk = K / 32;
    stage128x32(Ab, K, As[0], w, lane, 0);
    stage128x32(Wb, K, Bs[0], w, lane, 0);
    __syncthreads();

    for (int kt = 0; kt < nk; kt++) {
        const int cur = kt & 1;
        if (kt + 1 < nk) {
            stage128x32(Ab, K, As[cur ^ 1], w, lane, (kt + 1) * 32);
            stage128x32(Wb, K, Bs[cur ^ 1], w, lane, (kt + 1) * 32);
        }
        bf16x8 af[4], bfr[4];
#pragma unroll
        for (int i = 0; i < 4; i++)
            af[i] = *(const bf16x8*)(As[cur] + (wy * 64 + i * 16 + l15) * 32 + quad * 8);
#pragma unroll
        for (int j = 0; j < 4; j++)
            bfr[j] = *(const bf16x8*)(Bs[cur] + (wx * 64 + j * 16 + l15) * 32 + quad * 8);
#pragma unroll
        for (int i = 0; i < 4; i++)
#pragma unroll
            for (int j = 0; j < 4; j++)
                acc[i][j] = MFMA_BF16(af[i], bfr[j], acc[i][j], 0, 0, 0);
        __syncthreads();
    }

#pragma unroll
    for (int i = 0; i < 4; i++) {
#pragma unroll
        for (int j = 0; j < 4; j++) {
            const int col = n0 + wx * 64 + j * 16 + l15;
#pragma unroll
            for (int r = 0; r < 4; r++) {
                const int row = m0 + wy * 64 + i * 16 + quad * 4 + r;
                float v = acc[i][j][r];
                if constexpr (MODE == 0) {
                    if (col < Nq) {
                        qo[(size_t)row * Nq + col] = f2bf(v + bq[col]);
                    } else if (col < Nq + Nkv) {
                        int cn = col - Nq;
                        ko[(size_t)row * Nkv + cn] = f2bf(v + bk[cn]);
                    } else {
                        int cn = col - Nq - Nkv;
                        int b  = row / S, s = row - b * S;
                        int hk = cn >> 7, dh = cn & 127;   // Dh == 128
                        vo[(size_t)((b * Hkv + hk) * 128 + dh) * S + s] = f2bf(v + bv[cn]);
                    }
                } else {
                    fo[(size_t)row * N + col] = v + bq[col];
                }
            }
        }
    }
}

// Per-(token, head) LayerNorm over Dh=128 then RoPE. One wave per row-head.
__global__ __launch_bounds__(256) void ln_rope(
    const short* __restrict__ X, short* __restrict__ Y,
    const float* __restrict__ g, const float* __restrict__ bta,
    const float* __restrict__ cosp, const float* __restrict__ sinp,
    int H, int S)
{
    const int gw   = blockIdx.x * 4 + (threadIdx.x >> 6);
    const int lane = threadIdx.x & 63;
    const int h  = gw % H;
    const int rs = gw / H;          // b*S + s
    const int b  = rs / S;
    const int s  = rs - b * S;

    const short* x = X + ((size_t)rs * H + h) * 128;
    float x0 = bf2f(x[lane]), x1 = bf2f(x[lane + 64]);

    float sum = x0 + x1;
    float sq  = x0 * x0 + x1 * x1;
#pragma unroll
    for (int off = 32; off > 0; off >>= 1) {
        sum += __shfl_xor(sum, off, 64);
        sq  += __shfl_xor(sq, off, 64);
    }
    float mu  = sum * (1.f / 128.f);
    float var = sq * (1.f / 128.f) - mu * mu;
    float rinv = rsqrtf(var + 1e-5f);

    float y0 = (x0 - mu) * rinv * g[lane]      + bta[lane];
    float y1 = (x1 - mu) * rinv * g[lane + 64] + bta[lane + 64];

    float c0 = cosp[(size_t)s * 128 + lane];
    float c1 = cosp[(size_t)s * 128 + lane + 64];
    float s0 = sinp[(size_t)s * 128 + lane];
    float s1 = sinp[(size_t)s * 128 + lane + 64];

    float o0 = y0 * c0 - y1 * s0;
    float o1 = y1 * c1 + y0 * s1;

    short* yp = Y + ((size_t)(b * H + h) * S + s) * 128;
    yp[lane]      = f2bf(o0);
    yp[lane + 64] = f2bf(o1);
}

// Flash attention v3: transposed-score formulation + block-shared LDS staging.
// Q: bf16 (B,H,S,128). Kt: (B,Hkv,S,128). Vt: (B,Hkv,128,S). O: (B,S,H*128).
// K/V tiles (64 keys) staged per BLOCK into LDS in FRAGMENT ORDER via
// global_load_lds (global side = per-lane gather; LDS side = slab + lane*16B,
// satisfying the wave-uniform-dest rule). Double-buffered; prefetch of tile
// kt+1 issues before compute of kt, drains at the post-compute barrier.
// Fragment reads are contiguous ds_read_b128 (conflict-free, no VGPR
// long-liveness -> no more compiler load-sinking serialization).
// Scores D[key][query]: query = lane l15, key in-register; softmax per-lane.
__global__ __launch_bounds__(256, 2) void attn(
    const short* __restrict__ Q, const short* __restrict__ Kt,
    const short* __restrict__ Vt, short* __restrict__ O,
    int S, int H, int Hkv, int nrep, float scale)
{
    // 16 K slabs + 16 V slabs per buffer, 1 KB each (64 lanes x 16 B)
    __shared__ __align__(16) short Ks[2][16 * 512];
    __shared__ __align__(16) short Vs[2][16 * 512];
    __shared__ __align__(16) short P[4][16][72];

    const int w    = threadIdx.x >> 6;
    const int lane = threadIdx.x & 63;
    const int l15  = lane & 15;
    const int quad = lane >> 4;
    const int bh   = blockIdx.x;
    const int h    = bh % H;
    const int b    = bh / H;
    const int nyt  = gridDim.y;
    const int y    = blockIdx.y;
    // zigzag: pairs (y, y+nyt/2) get qblk summing to nyt-1 -> balanced per CU
    const int qblk = (y < (nyt >> 1)) ? (nyt - 1 - y) : (y - (nyt >> 1));
    const int hk   = h / nrep;
    const int m0   = qblk * 64 + w * 16;
    const int qpos = m0 + l15;          // this lane's query row

    const short* qb = Q  + (size_t)(b * H + h) * S * 128;
    const short* kb = Kt + (size_t)(b * Hkv + hk) * S * 128;
    const short* vb = Vt + (size_t)(b * Hkv + hk) * 128 * S;

    // stage K/V tile (64 keys starting at j0) into buffer `buf`.
    // Waves 0-1 stage the 16 K slabs; waves 2-3 the 16 V slabs.
    auto stage = [&](int buf, int j0) {
#pragma unroll
        for (int i = 0; i < 8; i++) {
            if (w < 2) {
                const int s = w * 8 + i;            // K slab: t = s>>2, c = s&3
                const int t = s >> 2, c = s & 3;
                gl_lds16(kb + (size_t)(j0 + t * 16 + l15) * 128 + c * 32 + quad * 8,
                         Ks[buf] + s * 512 + lane * 8);
            } else {
                const int u = (w - 2) * 8 + i;      // V slab: c = u>>1, half = u&1
                const int c = u >> 1, hf = u & 1;
                gl_lds16(vb + (size_t)(c * 16 + l15) * S + j0 + hf * 32 + quad * 8,
                         Vs[buf] + u * 512 + lane * 8);
            }
        }
    };

    bf16x8 qf[4];
#pragma unroll
    for (int c = 0; c < 4; c++)
        qf[c] = *(const bf16x8*)(qb + (size_t)(m0 + l15) * 128 + c * 32 + quad * 8);

    f32x4 of[8];     // D[dh][query]: r -> dh sub-index, lane l15 -> query
#pragma unroll
    for (int c = 0; c < 8; c++) of[c] = f32x4{0.f, 0.f, 0.f, 0.f};
    float m_s = -1e30f, l_s = 0.f;           // per-lane (per-query), unscaled max
    const float c2 = scale * 1.44269504f;    // fold scale+log2e into exp2

    const int nkt = qblk + 1;                // uniform across the block
    stage(0, 0);
    __syncthreads();

    for (int kt = 0; kt < nkt; kt++) {
        const int cur = kt & 1;
        if (kt + 1 < nkt) stage(cur ^ 1, (kt + 1) * 64);

        const short* Kb = Ks[cur];
        const short* Vb = Vs[cur];
        const int j0 = kt * 64;

        // sc[t] = D[key][query], keys j0 + t*16 + quad*4 + r, query = qpos
        f32x4 sc[4];
#pragma unroll
        for (int t = 0; t < 4; t++) sc[t] = f32x4{0.f, 0.f, 0.f, 0.f};
#pragma unroll
        for (int c = 0; c < 4; c++)
#pragma unroll
            for (int t = 0; t < 4; t++) {
                bf16x8 kf = *(const bf16x8*)(Kb + (t * 4 + c) * 512 + lane * 8);
                sc[t] = MFMA_BF16(kf, qf[c], sc[t], 0, 0, 0);
            }

        // mask (unscaled), in-lane max over 16 keys + 2 butterflies
        float v[4][4];
        float mx = -1e30f;
#pragma unroll
        for (int t = 0; t < 4; t++)
#pragma unroll
            for (int r = 0; r < 4; r++) {
                float s_ = sc[t][r];
                if (j0 + t * 16 + quad * 4 + r > qpos) s_ = -1e30f;
                v[t][r] = s_;
                mx = fmaxf(mx, s_);
            }
        mx = fmaxf(mx, __shfl_xor(mx, 16, 64));
        mx = fmaxf(mx, __shfl_xor(mx, 32, 64));
        float mnew  = fmaxf(m_s, mx);
        float mc    = mnew * c2;
        float alpha = exp2f(m_s * c2 - mc);
        float sum = 0.f;
        float p[4][4];
#pragma unroll
        for (int t = 0; t < 4; t++)
#pragma unroll
            for (int r = 0; r < 4; r++) {
                p[t][r] = exp2f(__builtin_fmaf(v[t][r], c2, -mc));
                sum += p[t][r];
            }
        sum += __shfl_xor(sum, 16, 64);
        sum += __shfl_xor(sum, 32, 64);
        l_s = l_s * alpha + sum;
        m_s = mnew;

#pragma unroll
        for (int c = 0; c < 8; c++) {
            f32x4 t = of[c];
            t[0] *= alpha; t[1] *= alpha; t[2] *= alpha; t[3] *= alpha;
            of[c] = t;
        }

        // P[key][query] -> LDS rows = query(l15), 4 consecutive keys per b64
#pragma unroll
        for (int t = 0; t < 4; t++) {
            s16x4 pk;
#pragma unroll
            for (int r = 0; r < 4; r++) pk[r] = f2bf(p[t][r]);
            *(s16x4*)(&P[w][l15][t * 16 + quad * 4]) = pk;
        }
        bf16x8 pb0 = *(const bf16x8*)(&P[w][l15][quad * 8]);
        bf16x8 pb1 = *(const bf16x8*)(&P[w][l15][32 + quad * 8]);

#pragma unroll
        for (int c = 0; c < 8; c++) {
            bf16x8 vf0 = *(const bf16x8*)(Vb + (c * 2 + 0) * 512 + lane * 8);
            bf16x8 vf1 = *(const bf16x8*)(Vb + (c * 2 + 1) * 512 + lane * 8);
            of[c] = MFMA_BF16(vf0, pb0, of[c], 0, 0, 0);
            of[c] = MFMA_BF16(vf1, pb1, of[c], 0, 0, 0);
        }
        __syncthreads();
    }

    const int HDh = H * 128;
    const float rinv = 1.0f / l_s;
    short* orow = O + ((size_t)b * S + qpos) * HDh + h * 128;
#pragma unroll
    for (int c = 0; c < 8; c++) {
        s16x4 ov;
#pragma unroll
        for (int r = 0; r < 4; r++) ov[r] = f2bf(of[c][r] * rinv);
        *(s16x4*)(orow + c * 16 + quad * 4) = ov;
    }
}

extern "C" void kernel_launch(void* const* d_in, const int* in_sizes, int n_in,
                              void* d_out, int out_size, void* d_ws, size_t ws_size,
                              hipStream_t stream) {
    const float* hs   = (const float*)d_in[0];
    const float* cosp = (const float*)d_in[1];
    const float* sinp = (const float*)d_in[2];
    const float* Wq   = (const float*)d_in[3];
    const float* bq   = (const float*)d_in[4];
    const float* Wk   = (const float*)d_in[5];
    const float* bk   = (const float*)d_in[6];
    const float* Wv   = (const float*)d_in[7];
    const float* bv   = (const float*)d_in[8];
    const float* Wo   = (const float*)d_in[9];
    const float* bo   = (const float*)d_in[10];
    const float* qg   = (const float*)d_in[11];
    const float* qb_  = (const float*)d_in[12];
    const float* kg   = (const float*)d_in[13];
    const float* kb_  = (const float*)d_in[14];

    const int Dh    = in_sizes[11];          // 128
    const int Dm    = in_sizes[10];          // 2048
    const int HDh   = in_sizes[4];           // 2048
    const int H     = HDh / Dh;              // 16
    const int HkvDh = in_sizes[6];           // 512
    const int Hkv   = HkvDh / Dh;            // 4
    const int S     = in_sizes[1] / Dh;      // 1024
    const int B     = in_sizes[0] / (S * Dm);// 2
    const int M     = B * S;                 // 2048
    const int nrep  = H / Hkv;               // 4

    // workspace layout; Wqb/Wkb/Wvb contiguous => packed (HDh+2*HkvDh, Dm)
    char* ws = (char*)d_ws;
    short* hsb  = (short*)ws;  ws += (size_t)M * Dm      * 2;  // 8 MB
    short* Wqb  = (short*)ws;  ws += (size_t)HDh * Dm    * 2;  // 8 MB
    short* Wkb  = (short*)ws;  ws += (size_t)HkvDh * Dm  * 2;  // 2 MB
    short* Wvb  = (short*)ws;  ws += (size_t)HkvDh * Dm  * 2;  // 2 MB
    short* Wob  = (short*)ws;  ws += (size_t)Dm * HDh    * 2;  // 8 MB
    short* qg16 = (short*)ws;  ws += (size_t)M * HDh     * 2;  // 8 MB
    short* kg16 = (short*)ws;  ws += (size_t)M * HkvDh   * 2;  // 2 MB
    short* qbuf = (short*)ws;  ws += (size_t)M * HDh     * 2;  // 8 MB
    short* kbuf = (short*)ws;  ws += (size_t)M * HkvDh   * 2;  // 2 MB
    short* vbuf = (short*)ws;  ws += (size_t)M * HkvDh   * 2;  // 2 MB
    short* abuf = qg16;   // alias: q-gemm output dead after ln_rope

    dim3 blk(256);
    const int n0 = M * Dm, n1 = HDh * Dm, n2 = HkvDh * Dm, n3 = HkvDh * Dm, n4 = Dm * HDh;
    cvt5<<<dim3((n0 + n1 + n2 + n3 + n4) / 1024), blk, 0, stream>>>(
        hs, hsb, n0, Wq, Wqb, n1, Wk, Wkb, n2, Wv, Wvb, n3, Wo, Wob, n4);

    const int Ntot = HDh + 2 * HkvDh;  // 3072
    gemm128<0><<<dim3(Ntot / 128, M / 128), blk, 0, stream>>>(
        hsb, Wqb, bq, bk, bv, qg16, kg16, vbuf, nullptr,
        M, Dm, S, Hkv, HDh, HkvDh, Ntot);

    ln_rope<<<dim3(M * H / 4),   blk, 0, stream>>>(qg16, qbuf, qg, qb_, cosp, sinp, H,   S);
    ln_rope<<<dim3(M * Hkv / 4), blk, 0, stream>>>(kg16, kbuf, kg, kb_, cosp, sinp, Hkv, S);

    const float scale = 1.0f / sqrtf((float)Dh);
    attn<<<dim3(H * B, S / 64), blk, 0, stream>>>(qbuf, kbuf, vbuf, abuf, S, H, Hkv, nrep, scale);

    gemm128<1><<<dim3(Dm / 128, M / 128), blk, 0, stream>>>(
        abuf, Wob, bo, nullptr, nullptr, nullptr, nullptr, nullptr, (float*)d_out,
        M, HDh, S, Hkv, Dm, 0, Dm);
}

// Round 8
// 256.243 us; speedup vs baseline: 2.2182x; 1.0559x over previous
//
#include <hip/hip_runtime.h>
#include <cmath>

typedef __attribute__((ext_vector_type(8))) short bf16x8;
typedef __attribute__((ext_vector_type(4))) short s16x4;
typedef __attribute__((ext_vector_type(4))) float f32x4;

#define MFMA_BF16 __builtin_amdgcn_mfma_f32_16x16x32_bf16

__device__ __forceinline__ float bf2f(short s) {
    unsigned u = ((unsigned)(unsigned short)s) << 16;
    return __builtin_bit_cast(float, u);
}
__device__ __forceinline__ short f2bf(float f) {
    unsigned u = __builtin_bit_cast(unsigned, f);
    u += 0x7fffu + ((u >> 16) & 1u);   // RNE
    return (short)(u >> 16);
}

__device__ __forceinline__ void gl_lds16(const short* gp, short* lp) {
    __builtin_amdgcn_global_load_lds(
        (const __attribute__((address_space(1))) unsigned int*)gp,
        (__attribute__((address_space(3))) unsigned int*)lp, 16, 0, 0);
}

// Fused fp32->bf16 conversion for 5 tensors; every segment size is a
// multiple of 1024 so each 256-thread block (4 elems/thread) stays in one.
__global__ __launch_bounds__(256) void cvt5(
    const float* s0, short* d0, int n0,
    const float* s1, short* d1, int n1,
    const float* s2, short* d2, int n2,
    const float* s3, short* d3, int n3,
    const float* s4, short* d4, int n4)
{
    long long i = (long long)blockIdx.x * 1024 + threadIdx.x * 4;
    const float* s; short* d;
    if      (i < n0)                  { s = s0; d = d0; }
    else if ((i -= n0) < n1)          { s = s1; d = d1; }
    else if ((i -= n1) < n2)          { s = s2; d = d2; }
    else if ((i -= n2) < n3)          { s = s3; d = d3; }
    else      { i -= n3;                s = s4; d = d4; }
    float4 v = *(const float4*)(s + i);
    s16x4 o;
    o[0] = f2bf(v.x); o[1] = f2bf(v.y); o[2] = f2bf(v.z); o[3] = f2bf(v.w);
    *(s16x4*)(d + i) = o;
}

// 128x64-tile GEMM: C = A @ W^T (+bias). 4 waves in 2x2, wave = 64x32
// (4x2 MFMA accs), BK=32, double-buffered LDS, global_load_lds staging.
// LDS layout = 1KB chunks of 16 rows x 32 cols, with XOR swizzle:
// lane L stages global (row = chunk*16 + L>>2, colq = (L&3)^((L>>2)&3)) to
// slot L -> in-row 64B permutation keeps global coalescing; fragment read
// idx = l15*4 + (quad^(l15&3)) spreads banks (4-way -> <=2-way conflicts).
// MODE 0: QKV fused epilogue; MODE 1: fp32 out + bias (bq).
template <int MODE>
__global__ __launch_bounds__(256) void gemm_t(
    const short* __restrict__ A, const short* __restrict__ W,
    const float* __restrict__ bq, const float* __restrict__ bk,
    const float* __restrict__ bv,
    short* __restrict__ qo, short* __restrict__ ko, short* __restrict__ vo,
    float* __restrict__ fo,
    int M, int K, int S, int Hkv, int Nq, int Nkv, int N)
{
    __shared__ __align__(16) short As[2][8 * 512];   // 128 rows
    __shared__ __align__(16) short Bs[2][4 * 512];   // 64 rows

    const int w    = threadIdx.x >> 6;
    const int lane = threadIdx.x & 63;
    const int l15  = lane & 15;
    const int quad = lane >> 4;
    const int wy   = w >> 1;
    const int wx   = w & 1;
    const int m0   = blockIdx.y * 128;
    const int n0   = blockIdx.x * 64;

    const short* Ab = A + (size_t)m0 * K;
    const short* Wb = W + (size_t)n0 * K;

    // staging: wave w stages A chunks 2w, 2w+1 and B chunk w
    const int srow = lane >> 2;                       // 0..15
    const int scol = ((lane & 3) ^ (srow & 3)) * 8;   // swizzled col group
    auto stage = [&](int buf, int kofs) {
#pragma unroll
        for (int i = 0; i < 2; i++) {
            const int c = 2 * w + i;
            gl_lds16(Ab + (size_t)(c * 16 + srow) * K + kofs + scol,
                     As[buf] + c * 512 + lane * 8);
        }
        gl_lds16(Wb + (size_t)(w * 16 + srow) * K + kofs + scol,
                 Bs[buf] + w * 512 + lane * 8);
    };

    f32x4 acc[4][2];
#pragma unroll
    for (int i = 0; i < 4; i++)
#pragma unroll
        for (int j = 0; j < 2; j++) acc[i][j] = f32x4{0.f, 0.f, 0.f, 0.f};

    const int ridx = (l15 * 4 + (quad ^ (l15 & 3))) * 8;  // fragment read offset
    const int nk = K / 32;
    stage(0, 0);
    __syncthreads();

    for (int kt = 0; kt < nk; kt++) {
        const int cur = kt & 1;
        if (kt + 1 < nk) stage(cur ^ 1, (kt + 1) * 32);

        bf16x8 af[4], bfr[2];
#pragma unroll
        for (int i = 0; i < 4; i++)
            af[i] = *(const bf16x8*)(As[cur] + (wy * 4 + i) * 512 + ridx);
#pragma unroll
        for (int j = 0; j < 2; j++)
            bfr[j] = *(const bf16x8*)(Bs[cur] + (wx * 2 + j) * 512 + ridx);
#pragma unroll
        for (int i = 0; i < 4; i++)
#pragma unroll
            for (int j = 0; j < 2; j++)
                acc[i][j] = MFMA_BF16(af[i], bfr[j], acc[i][j], 0, 0, 0);
        __syncthreads();
    }

#pragma unroll
    for (int i = 0; i < 4; i++) {
#pragma unroll
        for (int j = 0; j < 2; j++) {
            const int col = n0 + wx * 32 + j * 16 + l15;
#pragma unroll
            for (int r = 0; r < 4; r++) {
                const int row = m0 + wy * 64 + i * 16 + quad * 4 + r;
                float v = acc[i][j][r];
                if constexpr (MODE == 0) {
                    if (col < Nq) {
                        qo[(size_t)row * Nq + col] = f2bf(v + bq[col]);
                    } else if (col < Nq + Nkv) {
                        int cn = col - Nq;
                        ko[(size_t)row * Nkv + cn] = f2bf(v + bk[cn]);
                    } else {
                        int cn = col - Nq - Nkv;
                        int b  = row / S, s = row - b * S;
                        int hk = cn >> 7, dh = cn & 127;   // Dh == 128
                        vo[(size_t)((b * Hkv + hk) * 128 + dh) * S + s] = f2bf(v + bv[cn]);
                    }
                } else {
                    fo[(size_t)row * N + col] = v + bq[col];
                }
            }
        }
    }
}

// Fused per-(token, head) LayerNorm (Dh=128) + RoPE for Q and K in one
// launch. Blocks [0, nq/4) handle Q rows, the rest K rows.
__global__ __launch_bounds__(256) void ln_rope2(
    const short* __restrict__ Xq, short* __restrict__ Yq,
    const short* __restrict__ Xk, short* __restrict__ Yk,
    const float* __restrict__ qg, const float* __restrict__ qbe,
    const float* __restrict__ kg, const float* __restrict__ kbe,
    const float* __restrict__ cosp, const float* __restrict__ sinp,
    int H, int Hkv, int S, int nq)
{
    int gw = blockIdx.x * 4 + (threadIdx.x >> 6);
    const int lane = threadIdx.x & 63;
    const short* X; short* Y; const float* g; const float* bt; int Hc;
    if (gw < nq) { X = Xq; Y = Yq; g = qg; bt = qbe; Hc = H; }
    else { gw -= nq; X = Xk; Y = Yk; g = kg; bt = kbe; Hc = Hkv; }

    const int h  = gw % Hc;
    const int rs = gw / Hc;          // b*S + s
    const int b  = rs / S;
    const int s  = rs - b * S;

    const short* x = X + ((size_t)rs * Hc + h) * 128;
    float x0 = bf2f(x[lane]), x1 = bf2f(x[lane + 64]);

    float sum = x0 + x1;
    float sq  = x0 * x0 + x1 * x1;
#pragma unroll
    for (int off = 32; off > 0; off >>= 1) {
        sum += __shfl_xor(sum, off, 64);
        sq  += __shfl_xor(sq, off, 64);
    }
    float mu  = sum * (1.f / 128.f);
    float var = sq * (1.f / 128.f) - mu * mu;
    float rinv = rsqrtf(var + 1e-5f);

    float y0 = (x0 - mu) * rinv * g[lane]      + bt[lane];
    float y1 = (x1 - mu) * rinv * g[lane + 64] + bt[lane + 64];

    float c0 = cosp[(size_t)s * 128 + lane];
    float c1 = cosp[(size_t)s * 128 + lane + 64];
    float s0 = sinp[(size_t)s * 128 + lane];
    float s1 = sinp[(size_t)s * 128 + lane + 64];

    float o0 = y0 * c0 - y1 * s0;
    float o1 = y1 * c1 + y0 * s1;

    short* yp = Y + ((size_t)(b * Hc + h) * S + s) * 128;
    yp[lane]      = f2bf(o0);
    yp[lane + 64] = f2bf(o1);
}

// Flash attention v3: transposed-score formulation + block-shared LDS staging.
// Q: bf16 (B,H,S,128). Kt: (B,Hkv,S,128). Vt: (B,Hkv,128,S). O: (B,S,H*128).
__global__ __launch_bounds__(256, 2) void attn(
    const short* __restrict__ Q, const short* __restrict__ Kt,
    const short* __restrict__ Vt, short* __restrict__ O,
    int S, int H, int Hkv, int nrep, float scale)
{
    __shared__ __align__(16) short Ks[2][16 * 512];
    __shared__ __align__(16) short Vs[2][16 * 512];
    __shared__ __align__(16) short P[4][16][72];

    const int w    = threadIdx.x >> 6;
    const int lane = threadIdx.x & 63;
    const int l15  = lane & 15;
    const int quad = lane >> 4;
    const int bh   = blockIdx.x;
    const int h    = bh % H;
    const int b    = bh / H;
    const int nyt  = gridDim.y;
    const int y    = blockIdx.y;
    const int qblk = (y < (nyt >> 1)) ? (nyt - 1 - y) : (y - (nyt >> 1));
    const int hk   = h / nrep;
    const int m0   = qblk * 64 + w * 16;
    const int qpos = m0 + l15;

    const short* qb = Q  + (size_t)(b * H + h) * S * 128;
    const short* kb = Kt + (size_t)(b * Hkv + hk) * S * 128;
    const short* vb = Vt + (size_t)(b * Hkv + hk) * 128 * S;

    auto stage = [&](int buf, int j0) {
#pragma unroll
        for (int i = 0; i < 8; i++) {
            if (w < 2) {
                const int s = w * 8 + i;
                const int t = s >> 2, c = s & 3;
                gl_lds16(kb + (size_t)(j0 + t * 16 + l15) * 128 + c * 32 + quad * 8,
                         Ks[buf] + s * 512 + lane * 8);
            } else {
                const int u = (w - 2) * 8 + i;
                const int c = u >> 1, hf = u & 1;
                gl_lds16(vb + (size_t)(c * 16 + l15) * S + j0 + hf * 32 + quad * 8,
                         Vs[buf] + u * 512 + lane * 8);
            }
        }
    };

    bf16x8 qf[4];
#pragma unroll
    for (int c = 0; c < 4; c++)
        qf[c] = *(const bf16x8*)(qb + (size_t)(m0 + l15) * 128 + c * 32 + quad * 8);

    f32x4 of[8];
#pragma unroll
    for (int c = 0; c < 8; c++) of[c] = f32x4{0.f, 0.f, 0.f, 0.f};
    float m_s = -1e30f, l_s = 0.f;
    const float c2 = scale * 1.44269504f;

    const int nkt = qblk + 1;
    stage(0, 0);
    __syncthreads();

    for (int kt = 0; kt < nkt; kt++) {
        const int cur = kt & 1;
        if (kt + 1 < nkt) stage(cur ^ 1, (kt + 1) * 64);

        const short* Kb = Ks[cur];
        const short* Vb = Vs[cur];
        const int j0 = kt * 64;

        f32x4 sc[4];
#pragma unroll
        for (int t = 0; t < 4; t++) sc[t] = f32x4{0.f, 0.f, 0.f, 0.f};
#pragma unroll
        for (int c = 0; c < 4; c++)
#pragma unroll
            for (int t = 0; t < 4; t++) {
                bf16x8 kf = *(const bf16x8*)(Kb + (t * 4 + c) * 512 + lane * 8);
                sc[t] = MFMA_BF16(kf, qf[c], sc[t], 0, 0, 0);
            }

        float v[4][4];
        float mx = -1e30f;
#pragma unroll
        for (int t = 0; t < 4; t++)
#pragma unroll
            for (int r = 0; r < 4; r++) {
                float s_ = sc[t][r];
                if (j0 + t * 16 + quad * 4 + r > qpos) s_ = -1e30f;
                v[t][r] = s_;
                mx = fmaxf(mx, s_);
            }
        mx = fmaxf(mx, __shfl_xor(mx, 16, 64));
        mx = fmaxf(mx, __shfl_xor(mx, 32, 64));
        float mnew  = fmaxf(m_s, mx);
        float mc    = mnew * c2;
        float alpha = exp2f(m_s * c2 - mc);
        float sum = 0.f;
        float p[4][4];
#pragma unroll
        for (int t = 0; t < 4; t++)
#pragma unroll
            for (int r = 0; r < 4; r++) {
                p[t][r] = exp2f(__builtin_fmaf(v[t][r], c2, -mc));
                sum += p[t][r];
            }
        sum += __shfl_xor(sum, 16, 64);
        sum += __shfl_xor(sum, 32, 64);
        l_s = l_s * alpha + sum;
        m_s = mnew;

#pragma unroll
        for (int c = 0; c < 8; c++) {
            f32x4 t = of[c];
            t[0] *= alpha; t[1] *= alpha; t[2] *= alpha; t[3] *= alpha;
            of[c] = t;
        }

#pragma unroll
        for (int t = 0; t < 4; t++) {
            s16x4 pk;
#pragma unroll
            for (int r = 0; r < 4; r++) pk[r] = f2bf(p[t][r]);
            *(s16x4*)(&P[w][l15][t * 16 + quad * 4]) = pk;
        }
        bf16x8 pb0 = *(const bf16x8*)(&P[w][l15][quad * 8]);
        bf16x8 pb1 = *(const bf16x8*)(&P[w][l15][32 + quad * 8]);

#pragma unroll
        for (int c = 0; c < 8; c++) {
            bf16x8 vf0 = *(const bf16x8*)(Vb + (c * 2 + 0) * 512 + lane * 8);
            bf16x8 vf1 = *(const bf16x8*)(Vb + (c * 2 + 1) * 512 + lane * 8);
            of[c] = MFMA_BF16(vf0, pb0, of[c], 0, 0, 0);
            of[c] = MFMA_BF16(vf1, pb1, of[c], 0, 0, 0);
        }
        __syncthreads();
    }

    const int HDh = H * 128;
    const float rinv = 1.0f / l_s;
    short* orow = O + ((size_t)b * S + qpos) * HDh + h * 128;
#pragma unroll
    for (int c = 0; c < 8; c++) {
        s16x4 ov;
#pragma unroll
        for (int r = 0; r < 4; r++) ov[r] = f2bf(of[c][r] * rinv);
        *(s16x4*)(orow + c * 16 + quad * 4) = ov;
    }
}

extern "C" void kernel_launch(void* const* d_in, const int* in_sizes, int n_in,
                              void* d_out, int out_size, void* d_ws, size_t ws_size,
                              hipStream_t stream) {
    const float* hs   = (const float*)d_in[0];
    const float* cosp = (const float*)d_in[1];
    const float* sinp = (const float*)d_in[2];
    const float* Wq   = (const float*)d_in[3];
    const float* bq   = (const float*)d_in[4];
    const float* Wk   = (const float*)d_in[5];
    const float* bk   = (const float*)d_in[6];
    const float* Wv   = (const float*)d_in[7];
    const float* bv   = (const float*)d_in[8];
    const float* Wo   = (const float*)d_in[9];
    const float* bo   = (const float*)d_in[10];
    const float* qg   = (const float*)d_in[11];
    const float* qb_  = (const float*)d_in[12];
    const float* kg   = (const float*)d_in[13];
    const float* kb_  = (const float*)d_in[14];

    const int Dh    = in_sizes[11];          // 128
    const int Dm    = in_sizes[10];          // 2048
    const int HDh   = in_sizes[4];           // 2048
    const int H     = HDh / Dh;              // 16
    const int HkvDh = in_sizes[6];           // 512
    const int Hkv   = HkvDh / Dh;            // 4
    const int S     = in_sizes[1] / Dh;      // 1024
    const int B     = in_sizes[0] / (S * Dm);// 2
    const int M     = B * S;                 // 2048
    const int nrep  = H / Hkv;               // 4

    // workspace layout; Wqb/Wkb/Wvb contiguous => packed (HDh+2*HkvDh, Dm)
    char* ws = (char*)d_ws;
    short* hsb  = (short*)ws;  ws += (size_t)M * Dm      * 2;  // 8 MB
    short* Wqb  = (short*)ws;  ws += (size_t)HDh * Dm    * 2;  // 8 MB
    short* Wkb  = (short*)ws;  ws += (size_t)HkvDh * Dm  * 2;  // 2 MB
    short* Wvb  = (short*)ws;  ws += (size_t)HkvDh * Dm  * 2;  // 2 MB
    short* Wob  = (short*)ws;  ws += (size_t)Dm * HDh    * 2;  // 8 MB
    short* qg16 = (short*)ws;  ws += (size_t)M * HDh     * 2;  // 8 MB
    short* kg16 = (short*)ws;  ws += (size_t)M * HkvDh   * 2;  // 2 MB
    short* qbuf = (short*)ws;  ws += (size_t)M * HDh     * 2;  // 8 MB
    short* kbuf = (short*)ws;  ws += (size_t)M * HkvDh   * 2;  // 2 MB
    short* vbuf = (short*)ws;  ws += (size_t)M * HkvDh   * 2;  // 2 MB
    short* abuf = qg16;   // alias: q-gemm output dead after ln_rope

    dim3 blk(256);
    const int n0 = M * Dm, n1 = HDh * Dm, n2 = HkvDh * Dm, n3 = HkvDh * Dm, n4 = Dm * HDh;
    cvt5<<<dim3((n0 + n1 + n2 + n3 + n4) / 1024), blk, 0, stream>>>(
        hs, hsb, n0, Wq, Wqb, n1, Wk, Wkb, n2, Wv, Wvb, n3, Wo, Wob, n4);

    const int Ntot = HDh + 2 * HkvDh;  // 3072
    gemm_t<0><<<dim3(Ntot / 64, M / 128), blk, 0, stream>>>(
        hsb, Wqb, bq, bk, bv, qg16, kg16, vbuf, nullptr,
        M, Dm, S, Hkv, HDh, HkvDh, Ntot);

    const int nq = M * H;   // 32768 q row-heads
    ln_rope2<<<dim3((nq + M * Hkv) / 4), blk, 0, stream>>>(
        qg16, qbuf, kg16, kbuf, qg, qb_, kg, kb_, cosp, sinp, H, Hkv, S, nq);

    const float scale = 1.0f / sqrtf((float)Dh);
    attn<<<dim3(H * B, S / 64), blk, 0, stream>>>(qbuf, kbuf, vbuf, abuf, S, H, Hkv, nrep, scale);

    gemm_t<1><<<dim3(Dm / 64, M / 128), blk, 0, stream>>>(
        abuf, Wob, bo, nullptr, nullptr, nullptr, nullptr, nullptr, (float*)d_out,
        M, HDh, S, Hkv, Dm, 0, Dm);
}

// Round 9
// 243.030 us; speedup vs baseline: 2.3388x; 1.0544x over previous
//
#include <hip/hip_runtime.h>
#include <cmath>

typedef __attribute__((ext_vector_type(8))) short bf16x8;
typedef __attribute__((ext_vector_type(4))) short s16x4;
typedef __attribute__((ext_vector_type(4))) float f32x4;

#define MFMA_BF16 __builtin_amdgcn_mfma_f32_16x16x32_bf16

__device__ __forceinline__ float bf2f(short s) {
    unsigned u = ((unsigned)(unsigned short)s) << 16;
    return __builtin_bit_cast(float, u);
}
__device__ __forceinline__ short f2bf(float f) {
    unsigned u = __builtin_bit_cast(unsigned, f);
    u += 0x7fffu + ((u >> 16) & 1u);   // RNE
    return (short)(u >> 16);
}

__device__ __forceinline__ void gl_lds16(const short* gp, short* lp) {
    __builtin_amdgcn_global_load_lds(
        (const __attribute__((address_space(1))) unsigned int*)gp,
        (__attribute__((address_space(3))) unsigned int*)lp, 16, 0, 0);
}

// Fused fp32->bf16 conversion for 5 tensors; every segment size is a
// multiple of 1024 so each 256-thread block (4 elems/thread) stays in one.
__global__ __launch_bounds__(256) void cvt5(
    const float* s0, short* d0, int n0,
    const float* s1, short* d1, int n1,
    const float* s2, short* d2, int n2,
    const float* s3, short* d3, int n3,
    const float* s4, short* d4, int n4)
{
    long long i = (long long)blockIdx.x * 1024 + threadIdx.x * 4;
    const float* s; short* d;
    if      (i < n0)                  { s = s0; d = d0; }
    else if ((i -= n0) < n1)          { s = s1; d = d1; }
    else if ((i -= n1) < n2)          { s = s2; d = d2; }
    else if ((i -= n2) < n3)          { s = s3; d = d3; }
    else      { i -= n3;                s = s4; d = d4; }
    float4 v = *(const float4*)(s + i);
    s16x4 o;
    o[0] = f2bf(v.x); o[1] = f2bf(v.y); o[2] = f2bf(v.z); o[3] = f2bf(v.w);
    *(s16x4*)(d + i) = o;
}

// 128x64-tile GEMM: C = A @ W^T (+bias). 4 waves 2x2 (wave = 64x32, 4x2
// accs), BK=64 double-buffered LDS (48 KB), global_load_lds staging.
// LDS: per 32-K half, 1KB chunks of 16 rows; XOR swizzle f(row)=(row>>1)&3:
// lane L stages (row = chunk*16 + L>>2, kq = (L&3)^f(L>>2)) at slot L;
// fragment read slot = l15*4 + (quad^f(l15)) -> slot%8 distinct per octet
// (conflict-free b128), and the in-row 64B permutation keeps coalescing.
// BK=64 gives each staging load two 32-K compute phases before the barrier
// vmcnt(0) drain, and halves the barrier count.
// MODE 0: QKV fused epilogue; MODE 1: fp32 out + bias (bq).
template <int MODE>
__global__ __launch_bounds__(256) void gemm_t(
    const short* __restrict__ A, const short* __restrict__ W,
    const float* __restrict__ bq, const float* __restrict__ bk,
    const float* __restrict__ bv,
    short* __restrict__ qo, short* __restrict__ ko, short* __restrict__ vo,
    float* __restrict__ fo,
    int M, int K, int S, int Hkv, int Nq, int Nkv, int N)
{
    __shared__ __align__(16) short As[2][2 * 8 * 512];   // 2 halves x 8 chunks
    __shared__ __align__(16) short Bs[2][2 * 4 * 512];   // 2 halves x 4 chunks

    const int w    = threadIdx.x >> 6;
    const int lane = threadIdx.x & 63;
    const int l15  = lane & 15;
    const int quad = lane >> 4;
    const int wy   = w >> 1;
    const int wx   = w & 1;
    const int m0   = blockIdx.y * 128;
    const int n0   = blockIdx.x * 64;

    const short* Ab = A + (size_t)m0 * K;
    const short* Wb = W + (size_t)n0 * K;

    const int srow = lane >> 2;                              // 0..15
    const int scol = ((lane & 3) ^ ((srow >> 1) & 3)) * 8;   // swizzled col
    auto stage = [&](int buf, int kofs) {
#pragma unroll
        for (int h2 = 0; h2 < 2; h2++) {
#pragma unroll
            for (int i = 0; i < 2; i++) {
                const int c = 2 * w + i;
                gl_lds16(Ab + (size_t)(c * 16 + srow) * K + kofs + h2 * 32 + scol,
                         As[buf] + h2 * 4096 + c * 512 + lane * 8);
            }
            gl_lds16(Wb + (size_t)(w * 16 + srow) * K + kofs + h2 * 32 + scol,
                     Bs[buf] + h2 * 2048 + w * 512 + lane * 8);
        }
    };

    f32x4 acc[4][2];
#pragma unroll
    for (int i = 0; i < 4; i++)
#pragma unroll
        for (int j = 0; j < 2; j++) acc[i][j] = f32x4{0.f, 0.f, 0.f, 0.f};

    const int ridx = (l15 * 4 + (quad ^ ((l15 >> 1) & 3))) * 8;
    const int nk = K / 64;
    stage(0, 0);
    __syncthreads();

    for (int kt = 0; kt < nk; kt++) {
        const int cur = kt & 1;
        if (kt + 1 < nk) stage(cur ^ 1, (kt + 1) * 64);

#pragma unroll
        for (int h2 = 0; h2 < 2; h2++) {
            bf16x8 af[4], bfr[2];
#pragma unroll
            for (int i = 0; i < 4; i++)
                af[i] = *(const bf16x8*)(As[cur] + h2 * 4096 + (wy * 4 + i) * 512 + ridx);
#pragma unroll
            for (int j = 0; j < 2; j++)
                bfr[j] = *(const bf16x8*)(Bs[cur] + h2 * 2048 + (wx * 2 + j) * 512 + ridx);
#pragma unroll
            for (int i = 0; i < 4; i++)
#pragma unroll
                for (int j = 0; j < 2; j++)
                    acc[i][j] = MFMA_BF16(af[i], bfr[j], acc[i][j], 0, 0, 0);
        }
        __syncthreads();
    }

#pragma unroll
    for (int i = 0; i < 4; i++) {
#pragma unroll
        for (int j = 0; j < 2; j++) {
            const int col = n0 + wx * 32 + j * 16 + l15;
#pragma unroll
            for (int r = 0; r < 4; r++) {
                const int row = m0 + wy * 64 + i * 16 + quad * 4 + r;
                float v = acc[i][j][r];
                if constexpr (MODE == 0) {
                    if (col < Nq) {
                        qo[(size_t)row * Nq + col] = f2bf(v + bq[col]);
                    } else if (col < Nq + Nkv) {
                        int cn = col - Nq;
                        ko[(size_t)row * Nkv + cn] = f2bf(v + bk[cn]);
                    } else {
                        int cn = col - Nq - Nkv;
                        int b  = row / S, s = row - b * S;
                        int hk = cn >> 7, dh = cn & 127;   // Dh == 128
                        vo[(size_t)((b * Hkv + hk) * 128 + dh) * S + s] = f2bf(v + bv[cn]);
                    }
                } else {
                    fo[(size_t)row * N + col] = v + bq[col];
                }
            }
        }
    }
}

// Fused per-(token, head) LayerNorm (Dh=128) + RoPE for Q and K in one
// launch. Blocks [0, nq/4) handle Q rows, the rest K rows.
__global__ __launch_bounds__(256) void ln_rope2(
    const short* __restrict__ Xq, short* __restrict__ Yq,
    const short* __restrict__ Xk, short* __restrict__ Yk,
    const float* __restrict__ qg, const float* __restrict__ qbe,
    const float* __restrict__ kg, const float* __restrict__ kbe,
    const float* __restrict__ cosp, const float* __restrict__ sinp,
    int H, int Hkv, int S, int nq)
{
    int gw = blockIdx.x * 4 + (threadIdx.x >> 6);
    const int lane = threadIdx.x & 63;
    const short* X; short* Y; const float* g; const float* bt; int Hc;
    if (gw < nq) { X = Xq; Y = Yq; g = qg; bt = qbe; Hc = H; }
    else { gw -= nq; X = Xk; Y = Yk; g = kg; bt = kbe; Hc = Hkv; }

    const int h  = gw % Hc;
    const int rs = gw / Hc;          // b*S + s
    const int b  = rs / S;
    const int s  = rs - b * S;

    const short* x = X + ((size_t)rs * Hc + h) * 128;
    float x0 = bf2f(x[lane]), x1 = bf2f(x[lane + 64]);

    float sum = x0 + x1;
    float sq  = x0 * x0 + x1 * x1;
#pragma unroll
    for (int off = 32; off > 0; off >>= 1) {
        sum += __shfl_xor(sum, off, 64);
        sq  += __shfl_xor(sq, off, 64);
    }
    float mu  = sum * (1.f / 128.f);
    float var = sq * (1.f / 128.f) - mu * mu;
    float rinv = rsqrtf(var + 1e-5f);

    float y0 = (x0 - mu) * rinv * g[lane]      + bt[lane];
    float y1 = (x1 - mu) * rinv * g[lane + 64] + bt[lane + 64];

    float c0 = cosp[(size_t)s * 128 + lane];
    float c1 = cosp[(size_t)s * 128 + lane + 64];
    float s0 = sinp[(size_t)s * 128 + lane];
    float s1 = sinp[(size_t)s * 128 + lane + 64];

    float o0 = y0 * c0 - y1 * s0;
    float o1 = y1 * c1 + y0 * s1;

    short* yp = Y + ((size_t)(b * Hc + h) * S + s) * 128;
    yp[lane]      = f2bf(o0);
    yp[lane + 64] = f2bf(o1);
}

// Flash attention v3: transposed-score formulation + block-shared LDS staging.
// Q: bf16 (B,H,S,128). Kt: (B,Hkv,S,128). Vt: (B,Hkv,128,S). O: (B,S,H*128).
__global__ __launch_bounds__(256, 2) void attn(
    const short* __restrict__ Q, const short* __restrict__ Kt,
    const short* __restrict__ Vt, short* __restrict__ O,
    int S, int H, int Hkv, int nrep, float scale)
{
    __shared__ __align__(16) short Ks[2][16 * 512];
    __shared__ __align__(16) short Vs[2][16 * 512];
    __shared__ __align__(16) short P[4][16][72];

    const int w    = threadIdx.x >> 6;
    const int lane = threadIdx.x & 63;
    const int l15  = lane & 15;
    const int quad = lane >> 4;
    const int bh   = blockIdx.x;
    const int h    = bh % H;
    const int b    = bh / H;
    const int nyt  = gridDim.y;
    const int y    = blockIdx.y;
    const int qblk = (y < (nyt >> 1)) ? (nyt - 1 - y) : (y - (nyt >> 1));
    const int hk   = h / nrep;
    const int m0   = qblk * 64 + w * 16;
    const int qpos = m0 + l15;

    const short* qb = Q  + (size_t)(b * H + h) * S * 128;
    const short* kb = Kt + (size_t)(b * Hkv + hk) * S * 128;
    const short* vb = Vt + (size_t)(b * Hkv + hk) * 128 * S;

    auto stage = [&](int buf, int j0) {
#pragma unroll
        for (int i = 0; i < 8; i++) {
            if (w < 2) {
                const int s = w * 8 + i;
                const int t = s >> 2, c = s & 3;
                gl_lds16(kb + (size_t)(j0 + t * 16 + l15) * 128 + c * 32 + quad * 8,
                         Ks[buf] + s * 512 + lane * 8);
            } else {
                const int u = (w - 2) * 8 + i;
                const int c = u >> 1, hf = u & 1;
                gl_lds16(vb + (size_t)(c * 16 + l15) * S + j0 + hf * 32 + quad * 8,
                         Vs[buf] + u * 512 + lane * 8);
            }
        }
    };

    bf16x8 qf[4];
#pragma unroll
    for (int c = 0; c < 4; c++)
        qf[c] = *(const bf16x8*)(qb + (size_t)(m0 + l15) * 128 + c * 32 + quad * 8);

    f32x4 of[8];
#pragma unroll
    for (int c = 0; c < 8; c++) of[c] = f32x4{0.f, 0.f, 0.f, 0.f};
    float m_s = -1e30f, l_s = 0.f;
    const float c2 = scale * 1.44269504f;

    const int nkt = qblk + 1;
    stage(0, 0);
    __syncthreads();

    for (int kt = 0; kt < nkt; kt++) {
        const int cur = kt & 1;
        if (kt + 1 < nkt) stage(cur ^ 1, (kt + 1) * 64);

        const short* Kb = Ks[cur];
        const short* Vb = Vs[cur];
        const int j0 = kt * 64;

        f32x4 sc[4];
#pragma unroll
        for (int t = 0; t < 4; t++) sc[t] = f32x4{0.f, 0.f, 0.f, 0.f};
#pragma unroll
        for (int c = 0; c < 4; c++)
#pragma unroll
            for (int t = 0; t < 4; t++) {
                bf16x8 kf = *(const bf16x8*)(Kb + (t * 4 + c) * 512 + lane * 8);
                sc[t] = MFMA_BF16(kf, qf[c], sc[t], 0, 0, 0);
            }

        float v[4][4];
        float mx = -1e30f;
#pragma unroll
        for (int t = 0; t < 4; t++)
#pragma unroll
            for (int r = 0; r < 4; r++) {
                float s_ = sc[t][r];
                if (j0 + t * 16 + quad * 4 + r > qpos) s_ = -1e30f;
                v[t][r] = s_;
                mx = fmaxf(mx, s_);
            }
        mx = fmaxf(mx, __shfl_xor(mx, 16, 64));
        mx = fmaxf(mx, __shfl_xor(mx, 32, 64));
        float mnew  = fmaxf(m_s, mx);
        float mc    = mnew * c2;
        float alpha = exp2f(m_s * c2 - mc);
        float sum = 0.f;
        float p[4][4];
#pragma unroll
        for (int t = 0; t < 4; t++)
#pragma unroll
            for (int r = 0; r < 4; r++) {
                p[t][r] = exp2f(__builtin_fmaf(v[t][r], c2, -mc));
                sum += p[t][r];
            }
        sum += __shfl_xor(sum, 16, 64);
        sum += __shfl_xor(sum, 32, 64);
        l_s = l_s * alpha + sum;
        m_s = mnew;

#pragma unroll
        for (int c = 0; c < 8; c++) {
            f32x4 t = of[c];
            t[0] *= alpha; t[1] *= alpha; t[2] *= alpha; t[3] *= alpha;
            of[c] = t;
        }

#pragma unroll
        for (int t = 0; t < 4; t++) {
            s16x4 pk;
#pragma unroll
            for (int r = 0; r < 4; r++) pk[r] = f2bf(p[t][r]);
            *(s16x4*)(&P[w][l15][t * 16 + quad * 4]) = pk;
        }
        bf16x8 pb0 = *(const bf16x8*)(&P[w][l15][quad * 8]);
        bf16x8 pb1 = *(const bf16x8*)(&P[w][l15][32 + quad * 8]);

#pragma unroll
        for (int c = 0; c < 8; c++) {
            bf16x8 vf0 = *(const bf16x8*)(Vb + (c * 2 + 0) * 512 + lane * 8);
            bf16x8 vf1 = *(const bf16x8*)(Vb + (c * 2 + 1) * 512 + lane * 8);
            of[c] = MFMA_BF16(vf0, pb0, of[c], 0, 0, 0);
            of[c] = MFMA_BF16(vf1, pb1, of[c], 0, 0, 0);
        }
        __syncthreads();
    }

    const int HDh = H * 128;
    const float rinv = 1.0f / l_s;
    short* orow = O + ((size_t)b * S + qpos) * HDh + h * 128;
#pragma unroll
    for (int c = 0; c < 8; c++) {
        s16x4 ov;
#pragma unroll
        for (int r = 0; r < 4; r++) ov[r] = f2bf(of[c][r] * rinv);
        *(s16x4*)(orow + c * 16 + quad * 4) = ov;
    }
}

extern "C" void kernel_launch(void* const* d_in, const int* in_sizes, int n_in,
                              void* d_out, int out_size, void* d_ws, size_t ws_size,
                              hipStream_t stream) {
    const float* hs   = (const float*)d_in[0];
    const float* cosp = (const float*)d_in[1];
    const float* sinp = (const float*)d_in[2];
    const float* Wq   = (const float*)d_in[3];
    const float* bq   = (const float*)d_in[4];
    const float* Wk   = (const float*)d_in[5];
    const float* bk   = (const float*)d_in[6];
    const float* Wv   = (const float*)d_in[7];
    const float* bv   = (const float*)d_in[8];
    const float* Wo   = (const float*)d_in[9];
    const float* bo   = (const float*)d_in[10];
    const float* qg   = (const float*)d_in[11];
    const float* qb_  = (const float*)d_in[12];
    const float* kg   = (const float*)d_in[13];
    const float* kb_  = (const float*)d_in[14];

    const int Dh    = in_sizes[11];          // 128
    const int Dm    = in_sizes[10];          // 2048
    const int HDh   = in_sizes[4];           // 2048
    const int H     = HDh / Dh;              // 16
    const int HkvDh = in_sizes[6];           // 512
    const int Hkv   = HkvDh / Dh;            // 4
    const int S     = in_sizes[1] / Dh;      // 1024
    const int B     = in_sizes[0] / (S * Dm);// 2
    const int M     = B * S;                 // 2048
    const int nrep  = H / Hkv;               // 4

    // workspace layout; Wqb/Wkb/Wvb contiguous => packed (HDh+2*HkvDh, Dm)
    char* ws = (char*)d_ws;
    short* hsb  = (short*)ws;  ws += (size_t)M * Dm      * 2;  // 8 MB
    short* Wqb  = (short*)ws;  ws += (size_t)HDh * Dm    * 2;  // 8 MB
    short* Wkb  = (short*)ws;  ws += (size_t)HkvDh * Dm  * 2;  // 2 MB
    short* Wvb  = (short*)ws;  ws += (size_t)HkvDh * Dm  * 2;  // 2 MB
    short* Wob  = (short*)ws;  ws += (size_t)Dm * HDh    * 2;  // 8 MB
    short* qg16 = (short*)ws;  ws += (size_t)M * HDh     * 2;  // 8 MB
    short* kg16 = (short*)ws;  ws += (size_t)M * HkvDh   * 2;  // 2 MB
    short* qbuf = (short*)ws;  ws += (size_t)M * HDh     * 2;  // 8 MB
    short* kbuf = (short*)ws;  ws += (size_t)M * HkvDh   * 2;  // 2 MB
    short* vbuf = (short*)ws;  ws += (size_t)M * HkvDh   * 2;  // 2 MB
    short* abuf = qg16;   // alias: q-gemm output dead after ln_rope

    dim3 blk(256);
    const int n0 = M * Dm, n1 = HDh * Dm, n2 = HkvDh * Dm, n3 = HkvDh * Dm, n4 = Dm * HDh;
    cvt5<<<dim3((n0 + n1 + n2 + n3 + n4) / 1024), blk, 0, stream>>>(
        hs, hsb, n0, Wq, Wqb, n1, Wk, Wkb, n2, Wv, Wvb, n3, Wo, Wob, n4);

    const int Ntot = HDh + 2 * HkvDh;  // 3072
    gemm_t<0><<<dim3(Ntot / 64, M / 128), blk, 0, stream>>>(
        hsb, Wqb, bq, bk, bv, qg16, kg16, vbuf, nullptr,
        M, Dm, S, Hkv, HDh, HkvDh, Ntot);

    const int nq = M * H;   // 32768 q row-heads
    ln_rope2<<<dim3((nq + M * Hkv) / 4), blk, 0, stream>>>(
        qg16, qbuf, kg16, kbuf, qg, qb_, kg, kb_, cosp, sinp, H, Hkv, S, nq);

    const float scale = 1.0f / sqrtf((float)Dh);
    attn<<<dim3(H * B, S / 64), blk, 0, stream>>>(qbuf, kbuf, vbuf, abuf, S, H, Hkv, nrep, scale);

    gemm_t<1><<<dim3(Dm / 64, M / 128), blk, 0, stream>>>(
        abuf, Wob, bo, nullptr, nullptr, nullptr, nullptr, nullptr, (float*)d_out,
        M, HDh, S, Hkv, Dm, 0, Dm);
}